// Round 12
// baseline (2115.737 us; speedup 1.0000x reference)
//
// CaptionDecoder on MI355X — round 12: batch-local groups, ZERO grid barriers.
// r6-r11 lesson: grid barrier floor ~12us is intrinsic cross-XCD latency.
// Eliminate: 8-block group owns batch b fully (attention + its 256 gate cols);
// per step only 3 XCD-cheap 8-block mini-barriers (one split arrive/wait).
// Gate weights streamed from L2 via one-time [sub][k][col] coalesced repack;
// emb-gate term precomputed by bf16x3 GEMM.
#include <hip/hip_runtime.h>

#define E 512
#define H 512
#define V 32000
#define B 32
#define P 196
#define T 32
#define NB 256
#define NT 512

typedef __attribute__((ext_vector_type(8))) short s8v;    // 8 bf16
typedef __attribute__((ext_vector_type(4))) float f4v;    // 4 f32 acc

__device__ __forceinline__ float bf16_to_f(unsigned short u){
  return __uint_as_float(((unsigned)u) << 16);
}
__device__ __forceinline__ unsigned short f_to_bf16(float f){
  unsigned u = __float_as_uint(f);
  u += 0x7FFFu + ((u >> 16) & 1u);   // RNE
  return (unsigned short)(u >> 16);
}
__device__ __forceinline__ float fast_tanh(float x){
  float e = __expf(2.0f*x);
  return 1.0f - 2.0f/(e + 1.0f);
}
__device__ __forceinline__ float sigmoidf_(float x){
  return 1.0f/(1.0f + __expf(-x));
}
__device__ __forceinline__ void load_lds16(const unsigned short* g, unsigned short* l){
  __builtin_amdgcn_global_load_lds(
      (const __attribute__((address_space(1))) void*)g,
      (__attribute__((address_space(3))) void*)l, 16, 0, 0);
}
__device__ __forceinline__ float dot4(float4 a, float4 b){
  return a.x*b.x + a.y*b.y + a.z*b.z + a.w*b.w;
}

#define AT_SCOPE __HIP_MEMORY_SCOPE_AGENT
__device__ __forceinline__ float cohload(const float* p){
  return __hip_atomic_load(p, __ATOMIC_RELAXED, AT_SCOPE);
}
__device__ __forceinline__ void cohstore(float* p, float v){
  __hip_atomic_store(p, v, __ATOMIC_RELAXED, AT_SCOPE);
}
__device__ __forceinline__ unsigned cohldu(const unsigned* p){
  return __hip_atomic_load(p, __ATOMIC_RELAXED, AT_SCOPE);
}
__device__ __forceinline__ void cohstu(unsigned* p, unsigned v){
  __hip_atomic_store(p, v, __ATOMIC_RELAXED, AT_SCOPE);
}

// 8-block mini-barrier, split arrive/wait. __syncthreads in arrive drains the
// block's coherent stores (vmcnt 0) before the flag publish; all-relaxed.
__device__ __forceinline__ void bar_arrive(unsigned* my, unsigned gen){
  __syncthreads();
  if (threadIdx.x == 0) cohstu(my, gen);
}
__device__ __forceinline__ void bar_wait(const unsigned* base, unsigned gen){
  if (threadIdx.x < 64){
    for (;;){
      unsigned mn = 0xffffffffu;
      for (int i = (int)threadIdx.x; i < 8; i += 64){
        unsigned v = cohldu(base + i);
        mn = v < mn ? v : mn;
      }
      #pragma unroll
      for (int off = 32; off; off >>= 1){
        unsigned o2 = (unsigned)__shfl_xor((int)mn, off);
        mn = o2 < mn ? o2 : mn;
      }
      if (mn >= gen) break;
      __builtin_amdgcn_s_sleep(2);
    }
    __builtin_amdgcn_sched_barrier(0);
  }
  __syncthreads();
}
__device__ __forceinline__ void bar_mini(unsigned* my, const unsigned* base,
                                         unsigned gen){
  bar_arrive(my, gen);
  bar_wait(base, gen);
}

// ---------------------------------------------------------------------------
// f32 (strided) -> bf16 hi (+ optional lo residual). cols==512.
__global__ void split_kernel(const float* __restrict__ src, int src_ld, int src_coff,
                             int rows,
                             unsigned short* __restrict__ dhi, unsigned short* __restrict__ dlo,
                             int dst_ld, int dst_coff)
{
  int n = rows << 9;
  for (int i = blockIdx.x*blockDim.x + threadIdx.x; i < n; i += gridDim.x*blockDim.x){
    int r = i >> 9, c = i & 511;
    float x = src[(size_t)r*src_ld + src_coff + c];
    unsigned short h = f_to_bf16(x);
    dhi[(size_t)r*dst_ld + dst_coff + c] = h;
    if (dlo) dlo[(size_t)r*dst_ld + dst_coff + c] = f_to_bf16(x - bf16_to_f(h));
  }
}

// Embedding gather -> bf16 hi/lo rows (row = b*T + t)
__global__ void embed_kernel(const int* __restrict__ caps, const float* __restrict__ embW,
                             unsigned short* __restrict__ ehi, unsigned short* __restrict__ elo)
{
  int row = blockIdx.x;
  int cap = caps[row];
  const float* s = embW + (size_t)cap*E;
  for (int e = threadIdx.x; e < E; e += blockDim.x){
    float x = s[e];
    unsigned short h = f_to_bf16(x);
    ehi[(size_t)row*E + e] = h;
    elo[(size_t)row*E + e] = f_to_bf16(x - bf16_to_f(h));
  }
}

// mean over P, then h0 -> hgrp[0][b], c0 -> c_state
__global__ __launch_bounds__(512) void prep_kernel(
    const float* __restrict__ feats,
    const float* __restrict__ inith_W, const float* __restrict__ inith_b,
    const float* __restrict__ initc_W, const float* __restrict__ initc_b,
    float* __restrict__ hgrp, float* __restrict__ c_state)
{
  __shared__ float mf[E];
  const int b = blockIdx.x, tid = threadIdx.x;
  const float* fb = feats + (size_t)b*P*E + tid;
  float s = 0.f;
  for (int p = 0; p < P; ++p) s += fb[(size_t)p*E];
  mf[tid] = s * (1.0f/196.0f);
  __syncthreads();
  const float* wh = inith_W + (size_t)tid*E;
  const float* wc = initc_W + (size_t)tid*E;
  float h0 = inith_b[tid], c0 = initc_b[tid];
  #pragma unroll 4
  for (int e = 0; e < E; e += 4){
    float4 a4 = *(const float4*)(wh + e);
    float4 b4 = *(const float4*)(wc + e);
    float4 m4 = *(const float4*)(mf + e);
    h0 += dot4(a4, m4);
    c0 += dot4(b4, m4);
  }
  hgrp[(size_t)b*512 + tid] = h0;
  c_state[b*512 + tid] = c0;
}

// WhT[k][j] = attn_W[j][E + k]
__global__ __launch_bounds__(256) void transpose_wh_kernel(
    const float* __restrict__ attn_W, float* __restrict__ WhT)
{
  __shared__ float tile[64][65];
  const int jt = blockIdx.x & 7, kt = blockIdx.x >> 3;
  const int tx = threadIdx.x & 63, ty = threadIdx.x >> 6;
  for (int r = ty; r < 64; r += 4)
    tile[r][tx] = attn_W[(size_t)(jt*64 + r)*(E+H) + E + kt*64 + tx];
  __syncthreads();
  for (int r = ty; r < 64; r += 4)
    WhT[(size_t)(kt*64 + r)*512 + jt*64 + tx] = tile[tx][r];
}

// Wpack[sub][k][c]: k in [0,512) = Wih ctx-half of gate col; [512,1024) = Whh.
// c in [0,256): gcol = (c>>6)*512 + sub*64 + (c&63). Coalesced repack.
__global__ __launch_bounds__(256) void pack_wd_kernel(
    const float* __restrict__ Wih, const float* __restrict__ Whh,
    float* __restrict__ Wpack)
{
  __shared__ float tile[64][65];
  const int sub = blockIdx.x & 7, cg = (blockIdx.x >> 3) & 3, kg = blockIdx.x >> 5;
  const int tx = threadIdx.x & 63, ty = threadIdx.x >> 6;
  const int kbase = kg*64;
  for (int cl = ty; cl < 64; cl += 4){
    const int c = cg*64 + cl;
    const int gcol = (c >> 6)*512 + sub*64 + (c & 63);
    const int k = kbase + tx;
    tile[cl][tx] = (k < 512) ? Wih[(size_t)gcol*1024 + 512 + k]
                             : Whh[(size_t)gcol*512 + k - 512];
  }
  __syncthreads();
  for (int kk = ty; kk < 64; kk += 4)
    Wpack[((size_t)sub*1024 + kbase + kk)*256 + cg*64 + tx] = tile[tx][kk];
}

// ---------------------------------------------------------------------------
// m97-style bf16 GEMM: C = sum_passes A_p (MxK) * B_p(NxK)^T [+bias]
__global__ __launch_bounds__(256) void gemm_bt_kernel(
    const unsigned short* __restrict__ A0, const unsigned short* __restrict__ A1,
    const unsigned short* __restrict__ A2,
    const unsigned short* __restrict__ B0, const unsigned short* __restrict__ B1,
    const unsigned short* __restrict__ B2,
    float* __restrict__ Cc, const float* __restrict__ bias,
    int N, int K, int npasses, int mt, int swz)
{
  __shared__ __align__(16) unsigned short Al[128*32];
  __shared__ __align__(16) unsigned short Bl[128*32];
  const int tid = threadIdx.x;
  const int wid = tid >> 6, l = tid & 63;
  int f = blockIdx.x;
  if (swz) f = (f & 7)*((int)gridDim.x >> 3) + (f >> 3);
  const int m0 = (f % mt)*128, n0 = (f / mt)*128;
  const int wr = wid >> 1, wc = wid & 1;

  f4v acc[4][4];
  #pragma unroll
  for (int i = 0; i < 4; ++i)
    #pragma unroll
    for (int j = 0; j < 4; ++j) acc[i][j] = (f4v){0.f,0.f,0.f,0.f};

  const int s0 = tid, s1 = tid + 256;
  const int r0 = s0 >> 2, g0 = (s0 & 3) ^ ((r0 >> 1) & 3);
  const int r1 = s1 >> 2, g1 = (s1 & 3) ^ ((r1 >> 1) & 3);
  const int la = l & 15, ch = l >> 4;

  for (int pass = 0; pass < npasses; ++pass){
    const unsigned short* Ap = pass == 0 ? A0 : (pass == 1 ? A1 : A2);
    const unsigned short* Bp = pass == 0 ? B0 : (pass == 1 ? B1 : B2);
    for (int k0 = 0; k0 < K; k0 += 32){
      __syncthreads();
      load_lds16(Ap + (size_t)(m0 + r0)*K + k0 + g0*8, Al + s0*8);
      load_lds16(Ap + (size_t)(m0 + r1)*K + k0 + g1*8, Al + s1*8);
      load_lds16(Bp + (size_t)(n0 + r0)*K + k0 + g0*8, Bl + s0*8);
      load_lds16(Bp + (size_t)(n0 + r1)*K + k0 + g1*8, Bl + s1*8);
      __syncthreads();
      s8v av[4], bv[4];
      #pragma unroll
      for (int mi = 0; mi < 4; ++mi){
        int row = wr*64 + mi*16 + la;
        int cs = ch ^ ((row >> 1) & 3);
        av[mi] = *(const s8v*)(Al + (row*4 + cs)*8);
      }
      #pragma unroll
      for (int ni = 0; ni < 4; ++ni){
        int row = wc*64 + ni*16 + la;
        int cs = ch ^ ((row >> 1) & 3);
        bv[ni] = *(const s8v*)(Bl + (row*4 + cs)*8);
      }
      #pragma unroll
      for (int mi = 0; mi < 4; ++mi)
        #pragma unroll
        for (int ni = 0; ni < 4; ++ni)
          acc[mi][ni] = __builtin_amdgcn_mfma_f32_16x16x32_bf16(av[mi], bv[ni], acc[mi][ni], 0, 0, 0);
    }
  }
  #pragma unroll
  for (int mi = 0; mi < 4; ++mi){
    int row = m0 + wr*64 + mi*16 + (l >> 4)*4;
    #pragma unroll
    for (int ni = 0; ni < 4; ++ni){
      int col = n0 + wc*64 + ni*16 + (l & 15);
      float bb = bias ? bias[col] : 0.0f;
      #pragma unroll
      for (int r = 0; r < 4; ++r)
        Cc[(size_t)(row + r)*N + col] = acc[mi][ni][r] + bb;
    }
  }
}

// ---------------------------------------------------------------------------
// Persistent loop kernel, batch-local groups. blk = b*8 + sub.
// Group of 8 blocks owns batch b entirely: attention slices AND the LSTM
// (block -> j-slice sub*64..+64 x 4 gates = 256 gate cols of ITS batch).
// Per step: [A+B] mini1 [C] arrive2 [D-h-part] wait2 [D-ctx-part+update] mini3.
__global__ __launch_bounds__(512, 1) void loop_kernel(
    const float* __restrict__ feats, const float* __restrict__ feat_proj,
    const float* __restrict__ WhT, const float* __restrict__ attn_b,
    const float* __restrict__ v_w, const float* __restrict__ Wpack,
    const float* __restrict__ gates_emb,
    const float* __restrict__ b_ih, const float* __restrict__ b_hh,
    float* __restrict__ hgrp,          // [T+1][B][512]
    const float* __restrict__ c_init,
    float* __restrict__ ctxbuf,        // [T][B][512]
    float* __restrict__ sps,           // [T][B][8][200]
    unsigned short* __restrict__ hall_h, unsigned short* __restrict__ hall_l,
    unsigned* __restrict__ fm1, unsigned* __restrict__ fm2, unsigned* __restrict__ fm3)
{
  __shared__ float hs[512];
  __shared__ float ctxl[512];
  __shared__ float hwl[64];
  __shared__ float partA[8][72];
  __shared__ float aux[256];
  __shared__ float biasl[256];
  __shared__ float red[512];
  __shared__ float smx, sinv;

  const int blk = blockIdx.x, tid = threadIdx.x;
  const int b = blk >> 3, sub = blk & 7;
  const int gbase = blk & ~7;
  const int l = tid & 63, wv = tid >> 6;

  // ---- prologue ----
  float wreg[64];
  #pragma unroll
  for (int kk = 0; kk < 64; ++kk)
    wreg[kk] = WhT[(size_t)(wv*64 + kk)*512 + sub*64 + l];
  for (int c = tid; c < 256; c += NT){
    const int gcol = (c >> 6)*512 + sub*64 + (c & 63);
    biasl[c] = b_ih[gcol] + b_hh[gcol];
  }
  const float vl = v_w[sub*64 + l];
  const float ab = (tid < 64) ? attn_b[sub*64 + tid] : 0.f;
  float c_reg = 0.f;
  if (tid < 64) c_reg = c_init[b*512 + sub*64 + tid];

  // phase-D decomposition: thread = (dc: block-local col, kh: K half)
  const int dc = tid & 255;
  const int kh = tid >> 8;
  const float* wp_h = Wpack + ((size_t)sub*1024 + 512 + kh*256)*256 + dc;
  const float* wp_c = Wpack + ((size_t)sub*1024 +       kh*256)*256 + dc;
  __syncthreads();

  for (int t = 0; t < T; ++t){
    const unsigned gen = (unsigned)(t + 1);

    // ---- A: hWh[b][sub*64..+64) (register WhT slice x LDS-broadcast h) ----
    hs[tid] = cohload(hgrp + ((size_t)t*B + b)*512 + tid);
    __syncthreads();
    {
      const float* hk = hs + wv*64;
      float a = 0.f;
      #pragma unroll
      for (int kk = 0; kk < 64; ++kk) a += hk[kk] * wreg[kk];
      partA[wv][l] = a;
    }
    __syncthreads();
    if (tid < 64){
      float s = ab;
      #pragma unroll
      for (int k = 0; k < 8; ++k) s += partA[k][tid];
      hwl[tid] = s;
    }
    __syncthreads();

    // ---- B: partial scores over own j-slice ----
    {
      const float hj = hwl[l];
      float* spw = sps + (((size_t)t*B + b)*8 + sub)*200;
      for (int p = wv; p < P; p += 8){
        float fp = feat_proj[((size_t)b*P + p)*512 + sub*64 + l];
        float e2 = vl * fast_tanh(fp + hj);
        #pragma unroll
        for (int off = 32; off; off >>= 1) e2 += __shfl_xor(e2, off);
        if (l == 0) cohstore(spw + p, e2);
      }
    }
    bar_mini(fm1 + blk, fm1 + gbase, gen);

    // ---- C: reduce partials -> softmax -> ctx slice ----
    {
      float sc_v = -1e30f;
      if (tid < P){
        const float* sp = sps + ((size_t)t*B + b)*8*200 + tid;
        float s8 = 0.f;
        #pragma unroll
        for (int k = 0; k < 8; ++k) s8 += cohload(sp + k*200);
        sc_v = s8;
      }
      if (tid < 256) aux[tid] = sc_v;
      __syncthreads();
      if (tid < 64){
        float m = -1e30f;
        #pragma unroll
        for (int i = 0; i < 4; ++i) m = fmaxf(m, aux[tid + i*64]);
        #pragma unroll
        for (int off = 32; off; off >>= 1) m = fmaxf(m, __shfl_xor(m, off));
        if (tid == 0) smx = m;
      }
      __syncthreads();
      float al = (tid < P) ? __expf(sc_v - smx) : 0.f;
      if (tid < 256) aux[tid] = al;
      __syncthreads();
      if (tid < 64){
        float s = 0.f;
        #pragma unroll
        for (int i = 0; i < 4; ++i) s += aux[tid + i*64];
        #pragma unroll
        for (int off = 32; off; off >>= 1) s += __shfl_xor(s, off);
        if (tid == 0) sinv = 1.0f/s;
      }
      __syncthreads();
      float a = 0.f;
      for (int p = wv; p < P; p += 8)
        a += aux[p] * feats[((size_t)b*P + p)*512 + sub*64 + l];
      partA[wv][l] = a;
      __syncthreads();
      if (tid < 64){
        float s = 0.f;
        #pragma unroll
        for (int k = 0; k < 8; ++k) s += partA[k][tid];
        cohstore(ctxbuf + ((size_t)t*B + b)*512 + sub*64 + tid, s * sinv);
      }
    }
    bar_arrive(fm2 + blk, gen);

    // ---- D part 1: Whh-part dots (needs only hs, overlaps ctx publish) ----
    float acc0 = 0.f, acc1 = 0.f, acc2 = 0.f, acc3 = 0.f;
    {
      const float* hk = hs + kh*256;
      #pragma unroll 8
      for (int k = 0; k < 256; k += 4){
        acc0 += wp_h[(size_t)(k+0)*256] * hk[k+0];
        acc1 += wp_h[(size_t)(k+1)*256] * hk[k+1];
        acc2 += wp_h[(size_t)(k+2)*256] * hk[k+2];
        acc3 += wp_h[(size_t)(k+3)*256] * hk[k+3];
      }
    }
    bar_wait(fm2 + gbase, gen);

    // ---- D part 2: ctx-part dots + LSTM update ----
    ctxl[tid] = cohload(ctxbuf + ((size_t)t*B + b)*512 + tid);
    __syncthreads();
    {
      const float* ck = ctxl + kh*256;
      #pragma unroll 8
      for (int k = 0; k < 256; k += 4){
        acc0 += wp_c[(size_t)(k+0)*256] * ck[k+0];
        acc1 += wp_c[(size_t)(k+1)*256] * ck[k+1];
        acc2 += wp_c[(size_t)(k+2)*256] * ck[k+2];
        acc3 += wp_c[(size_t)(k+3)*256] * ck[k+3];
      }
      red[dc*2 + kh] = (acc0 + acc1) + (acc2 + acc3);
    }
    __syncthreads();
    if (tid < 64){
      const float* ge = gates_emb + ((size_t)b*T + t)*2048;
      float gv[4];
      #pragma unroll
      for (int g = 0; g < 4; ++g){
        const int c = g*64 + tid;
        gv[g] = red[c*2] + red[c*2 + 1] + biasl[c] + ge[g*512 + sub*64 + tid];
      }
      const float i_ = sigmoidf_(gv[0]);
      const float f_ = sigmoidf_(gv[1]);
      const float g_ = fast_tanh(gv[2]);
      const float o_ = sigmoidf_(gv[3]);
      const int j = sub*64 + tid;
      const float c_new = f_*c_reg + i_*g_;
      const float h_new = o_*fast_tanh(c_new);
      c_reg = c_new;
      cohstore(hgrp + ((size_t)(t+1)*B + b)*512 + j, h_new);
      const unsigned short hh = f_to_bf16(h_new);
      hall_h[((size_t)b*T + t)*512 + j] = hh;
      hall_l[((size_t)b*T + t)*512 + j] = f_to_bf16(h_new - bf16_to_f(hh));
    }
    bar_mini(fm3 + blk, fm3 + gbase, gen);
  }
}

// ---------------------------------------------------------------------------
extern "C" void kernel_launch(void* const* d_in, const int* in_sizes, int n_in,
                              void* d_out, int out_size, void* d_ws, size_t ws_size,
                              hipStream_t stream)
{
  (void)in_sizes; (void)n_in; (void)out_size;
  const float* features = (const float*)d_in[0];
  const int*   captions = (const int*)d_in[1];
  const float* embed_W  = (const float*)d_in[2];
  const float* attn_W   = (const float*)d_in[3];
  const float* attn_b   = (const float*)d_in[4];
  const float* v_w      = (const float*)d_in[5];
  const float* W_ih     = (const float*)d_in[6];
  const float* W_hh     = (const float*)d_in[7];
  const float* b_ih     = (const float*)d_in[8];
  const float* b_hh     = (const float*)d_in[9];
  const float* lin_W    = (const float*)d_in[10];
  const float* lin_b    = (const float*)d_in[11];
  const float* inith_W  = (const float*)d_in[12];
  const float* inith_b  = (const float*)d_in[13];
  const float* initc_W  = (const float*)d_in[14];
  const float* initc_b  = (const float*)d_in[15];

  // "early" scratch in d_out (131MB; all dead before final logits GEMM)
  char* o = (char*)d_out;
  unsigned short* feat_bf   = (unsigned short*)o; o += (size_t)(B*P)*E*2;   // 6.4MB
  unsigned short* Wf_bf     = (unsigned short*)o; o += (size_t)H*E*2;       // 0.5MB
  float*          feat_proj = (float*)o;          o += (size_t)(B*P)*H*4;   // 12.9MB
  unsigned short* emb_hi    = (unsigned short*)o; o += (size_t)(B*T)*E*2;   // 1.05MB
  unsigned short* emb_lo    = (unsigned short*)o; o += (size_t)(B*T)*E*2;
  unsigned short* Wihe_hi   = (unsigned short*)o; o += (size_t)2048*512*2;  // 2.1MB
  unsigned short* Wihe_lo   = (unsigned short*)o; o += (size_t)2048*512*2;
  float*          gates_emb = (float*)o;          o += (size_t)(B*T)*2048*4;// 8.4MB
  float*          Wpack     = (float*)o;          o += (size_t)8*1024*256*4;// 8.4MB

  // persistent scratch in d_ws
  const size_t SZ_LIN  = (size_t)V*H*2;               // 32.77MB
  const size_t SZ_HALL = (size_t)(B*T)*H*2;           // 1MB
  const size_t SZ_CTX  = (size_t)T*B*512*4;           // 2.1MB
  const size_t SZ_HG   = (size_t)(T+1)*B*512*4;       // 2.16MB
  const size_t SZ_SPS  = (size_t)T*B*8*200*4;         // 6.55MB
  const size_t SZ_ST   = (size_t)B*H*4;               // 64KB
  const size_t SZ_WHT  = (size_t)H*H*4;               // 1MB
  const size_t SZ_FLG  = 4096;
  const size_t need_wo = SZ_LIN + 2*SZ_HALL + SZ_CTX + SZ_HG + SZ_SPS + SZ_ST + SZ_WHT + SZ_FLG;
  const bool three = (ws_size >= need_wo + SZ_LIN);

  char* w = (char*)d_ws;
  unsigned short* lin_hi  = (unsigned short*)w; w += SZ_LIN;
  unsigned short* lin_lo  = (unsigned short*)w; if (three) w += SZ_LIN;
  unsigned short* hall_hi = (unsigned short*)w; w += SZ_HALL;
  unsigned short* hall_lo = (unsigned short*)w; w += SZ_HALL;
  float*          ctxbuf  = (float*)w;          w += SZ_CTX;
  float*          hgrp    = (float*)w;          w += SZ_HG;
  float*          sps     = (float*)w;          w += SZ_SPS;
  float*          c_state = (float*)w;          w += SZ_ST;
  float*          WhT_ws  = (float*)w;          w += SZ_WHT;
  unsigned*       flags   = (unsigned*)w;       w += SZ_FLG;
  unsigned* fm1 = flags;           // [256]
  unsigned* fm2 = flags + 256;     // [256]
  unsigned* fm3 = flags + 512;     // [256]

  // --- conversions / gathers / init ---
  split_kernel<<<2048, 256, 0, stream>>>(features, E, 0, B*P, feat_bf, nullptr, E, 0);
  split_kernel<<<256, 256, 0, stream>>>(attn_W, E+H, 0, H, Wf_bf, nullptr, E, 0);
  split_kernel<<<2048, 256, 0, stream>>>(lin_W, 512, 0, V, lin_hi, three ? lin_lo : nullptr, 512, 0);
  split_kernel<<<1024, 256, 0, stream>>>(W_ih, 1024, 0, 2048, Wihe_hi, Wihe_lo, 512, 0);
  embed_kernel<<<B*T, 256, 0, stream>>>(captions, embed_W, emb_hi, emb_lo);
  prep_kernel<<<B, 512, 0, stream>>>(features, inith_W, inith_b, initc_W, initc_b,
                                     hgrp, c_state);
  transpose_wh_kernel<<<64, 256, 0, stream>>>(attn_W, WhT_ws);
  pack_wd_kernel<<<512, 256, 0, stream>>>(W_ih, W_hh, Wpack);
  hipMemsetAsync(flags, 0, SZ_FLG, stream);

  // feat_proj = features @ Wf^T (bf16 1-pass; error damped through tanh/softmax)
  gemm_bt_kernel<<<(B*P/128)*(E/128), 256, 0, stream>>>(
      feat_bf, feat_bf, feat_bf, Wf_bf, Wf_bf, Wf_bf,
      feat_proj, nullptr, E, E, 1, B*P/128, 0);
  // gates_emb = emb @ W_ih[:, :512]^T (bf16x3 exact-ish)
  gemm_bt_kernel<<<(B*T/128)*(2048/128), 256, 0, stream>>>(
      emb_hi, emb_lo, emb_hi, Wihe_hi, Wihe_hi, Wihe_lo,
      gates_emb, nullptr, 2048, 512, 3, B*T/128, 1);

  // --- the whole recurrence: one persistent kernel, zero grid barriers ---
  loop_kernel<<<NB, NT, 0, stream>>>(
      features, feat_proj, WhT_ws, attn_b, v_w, Wpack, gates_emb, b_ih, b_hh,
      hgrp, c_state, ctxbuf, sps, hall_hi, hall_lo, fm1, fm2, fm3);

  // --- logits = h_all @ lin_W^T + lin_b (bf16x3, XCD-swizzled grid) ---
  gemm_bt_kernel<<<(V/128)*(B*T/128), 256, 0, stream>>>(
      hall_hi, hall_lo, hall_hi, lin_hi, lin_hi, three ? lin_lo : lin_hi,
      (float*)d_out, lin_b, V, H, three ? 3 : 2, B*T/128, 1);
}

// Round 14
// 2053.926 us; speedup vs baseline: 1.0301x; 1.0301x over previous
//
// CaptionDecoder on MI355X — round 14: r13 content, scanner folded into block 0.
// r13 post-mortem: 257th (scanner) block never co-resident (1 block/CU x 256
// CUs) -> deadlock. Fix: grid=256, block 0 scans inline AFTER its D-h work so
// the scan sits inside the barrier window. Keeps: D-h hidden under g1,
// gates_emb hoist (D K=1024), fpreg, hall stores in g2 window, sps [p][8].
#include <hip/hip_runtime.h>

#define E 512
#define H 512
#define V 32000
#define B 32
#define P 196
#define T 32
#define NB 256
#define NT 512

typedef __attribute__((ext_vector_type(8))) short s8v;    // 8 bf16
typedef __attribute__((ext_vector_type(4))) float f4v;    // 4 f32 acc

__device__ __forceinline__ float bf16_to_f(unsigned short u){
  return __uint_as_float(((unsigned)u) << 16);
}
__device__ __forceinline__ unsigned short f_to_bf16(float f){
  unsigned u = __float_as_uint(f);
  u += 0x7FFFu + ((u >> 16) & 1u);   // RNE
  return (unsigned short)(u >> 16);
}
__device__ __forceinline__ float fast_tanh(float x){
  float e = __expf(2.0f*x);
  return 1.0f - 2.0f/(e + 1.0f);
}
__device__ __forceinline__ float sigmoidf_(float x){
  return 1.0f/(1.0f + __expf(-x));
}
__device__ __forceinline__ void load_lds16(const unsigned short* g, unsigned short* l){
  __builtin_amdgcn_global_load_lds(
      (const __attribute__((address_space(1))) void*)g,
      (__attribute__((address_space(3))) void*)l, 16, 0, 0);
}
__device__ __forceinline__ float dot4(float4 a, float4 b){
  return a.x*b.x + a.y*b.y + a.z*b.z + a.w*b.w;
}

#define AT_SCOPE __HIP_MEMORY_SCOPE_AGENT
__device__ __forceinline__ void cohstore(float* p, float v){
  __hip_atomic_store(p, v, __ATOMIC_RELAXED, AT_SCOPE);
}
__device__ __forceinline__ unsigned cohldu(const unsigned* p){
  return __hip_atomic_load(p, __ATOMIC_RELAXED, AT_SCOPE);
}
__device__ __forceinline__ void cohstu(unsigned* p, unsigned v){
  __hip_atomic_store(p, v, __ATOMIC_RELAXED, AT_SCOPE);
}

// 8-block mini-barrier (XCD-local group), all relaxed (r9-proven ordering:
// __syncthreads drains vmcnt -> block's coherent stores complete before flag).
__device__ __forceinline__ void bar_mini(unsigned* my, const unsigned* base,
                                         unsigned gen){
  __syncthreads();
  if (threadIdx.x == 0) cohstu(my, gen);
  if (threadIdx.x < 64){
    for (;;){
      unsigned mn = 0xffffffffu;
      for (int i = (int)threadIdx.x; i < 8; i += 64){
        unsigned v = cohldu(base + i);
        mn = v < mn ? v : mn;
      }
      #pragma unroll
      for (int off = 32; off; off >>= 1){
        unsigned o2 = (unsigned)__shfl_xor((int)mn, off);
        mn = o2 < mn ? o2 : mn;
      }
      if (mn >= gen) break;
      __builtin_amdgcn_s_sleep(2);
    }
    __builtin_amdgcn_sched_barrier(0);
  }
  __syncthreads();
}

// Grid barrier pieces: arrive publishes own flag; block 0 scans (inline, after
// its hidden work) and publishes gd; wait polls only gd.
__device__ __forceinline__ void gbar_arrive(unsigned* flags, unsigned gen){
  __syncthreads();
  if (threadIdx.x == 0) cohstu(flags + blockIdx.x, gen);
}
__device__ __forceinline__ void scan_publish(const unsigned* flags, unsigned* gd,
                                             unsigned gen){
  if (threadIdx.x < 64){
    for (;;){
      unsigned mn = 0xffffffffu;
      #pragma unroll
      for (int i = 0; i < 4; ++i){
        unsigned v = cohldu(flags + threadIdx.x + i*64);
        mn = v < mn ? v : mn;
      }
      #pragma unroll
      for (int off = 32; off; off >>= 1){
        unsigned o2 = (unsigned)__shfl_xor((int)mn, off);
        mn = o2 < mn ? o2 : mn;
      }
      if (mn >= gen) break;
      __builtin_amdgcn_s_sleep(1);
    }
    if (threadIdx.x == 0) cohstu(gd, gen);
  }
}
__device__ __forceinline__ void gbar_wait(const unsigned* gd, unsigned gen){
  if (threadIdx.x == 0){
    while (cohldu(gd) < gen) __builtin_amdgcn_s_sleep(2);
    __builtin_amdgcn_sched_barrier(0);
  }
  __syncthreads();
}

// ---------------------------------------------------------------------------
// f32 (strided) -> bf16 hi (+ optional lo residual). cols==512.
__global__ void split_kernel(const float* __restrict__ src, int src_ld, int src_coff,
                             int rows,
                             unsigned short* __restrict__ dhi, unsigned short* __restrict__ dlo,
                             int dst_ld, int dst_coff)
{
  int n = rows << 9;
  for (int i = blockIdx.x*blockDim.x + threadIdx.x; i < n; i += gridDim.x*blockDim.x){
    int r = i >> 9, c = i & 511;
    float x = src[(size_t)r*src_ld + src_coff + c];
    unsigned short h = f_to_bf16(x);
    dhi[(size_t)r*dst_ld + dst_coff + c] = h;
    if (dlo) dlo[(size_t)r*dst_ld + dst_coff + c] = f_to_bf16(x - bf16_to_f(h));
  }
}

// Embedding gather -> bf16 hi/lo rows (row = b*T + t)
__global__ void embed_kernel(const int* __restrict__ caps, const float* __restrict__ embW,
                             unsigned short* __restrict__ ehi, unsigned short* __restrict__ elo)
{
  int row = blockIdx.x;
  int cap = caps[row];
  const float* s = embW + (size_t)cap*E;
  for (int e = threadIdx.x; e < E; e += blockDim.x){
    float x = s[e];
    unsigned short h = f_to_bf16(x);
    ehi[(size_t)row*E + e] = h;
    elo[(size_t)row*E + e] = f_to_bf16(x - bf16_to_f(h));
  }
}

// mean over P, then h0 -> hgrp[0][b], c0 -> c_state
__global__ __launch_bounds__(512) void prep_kernel(
    const float* __restrict__ feats,
    const float* __restrict__ inith_W, const float* __restrict__ inith_b,
    const float* __restrict__ initc_W, const float* __restrict__ initc_b,
    float* __restrict__ hgrp, float* __restrict__ c_state)
{
  __shared__ float mf[E];
  const int b = blockIdx.x, tid = threadIdx.x;
  const float* fb = feats + (size_t)b*P*E + tid;
  float s = 0.f;
  for (int p = 0; p < P; ++p) s += fb[(size_t)p*E];
  mf[tid] = s * (1.0f/196.0f);
  __syncthreads();
  const float* wh = inith_W + (size_t)tid*E;
  const float* wc = initc_W + (size_t)tid*E;
  float h0 = inith_b[tid], c0 = initc_b[tid];
  #pragma unroll 4
  for (int e = 0; e < E; e += 4){
    float4 a4 = *(const float4*)(wh + e);
    float4 b4 = *(const float4*)(wc + e);
    float4 m4 = *(const float4*)(mf + e);
    h0 += dot4(a4, m4);
    c0 += dot4(b4, m4);
  }
  hgrp[(size_t)b*512 + tid] = h0;
  c_state[b*512 + tid] = c0;
}

// WhT[k][j] = attn_W[j][E + k]
__global__ __launch_bounds__(256) void transpose_wh_kernel(
    const float* __restrict__ attn_W, float* __restrict__ WhT)
{
  __shared__ float tile[64][65];
  const int jt = blockIdx.x & 7, kt = blockIdx.x >> 3;
  const int tx = threadIdx.x & 63, ty = threadIdx.x >> 6;
  for (int r = ty; r < 64; r += 4)
    tile[r][tx] = attn_W[(size_t)(jt*64 + r)*(E+H) + E + kt*64 + tx];
  __syncthreads();
  for (int r = ty; r < 64; r += 4)
    WhT[(size_t)(kt*64 + r)*512 + jt*64 + tx] = tile[tx][r];
}

// ---------------------------------------------------------------------------
// m97-style bf16 GEMM: C = sum_passes A_p (MxK) * B_p(NxK)^T [+bias]
__global__ __launch_bounds__(256) void gemm_bt_kernel(
    const unsigned short* __restrict__ A0, const unsigned short* __restrict__ A1,
    const unsigned short* __restrict__ A2,
    const unsigned short* __restrict__ B0, const unsigned short* __restrict__ B1,
    const unsigned short* __restrict__ B2,
    float* __restrict__ Cc, const float* __restrict__ bias,
    int N, int K, int npasses, int mt, int swz)
{
  __shared__ __align__(16) unsigned short Al[128*32];
  __shared__ __align__(16) unsigned short Bl[128*32];
  const int tid = threadIdx.x;
  const int wid = tid >> 6, l = tid & 63;
  int f = blockIdx.x;
  if (swz) f = (f & 7)*((int)gridDim.x >> 3) + (f >> 3);
  const int m0 = (f % mt)*128, n0 = (f / mt)*128;
  const int wr = wid >> 1, wc = wid & 1;

  f4v acc[4][4];
  #pragma unroll
  for (int i = 0; i < 4; ++i)
    #pragma unroll
    for (int j = 0; j < 4; ++j) acc[i][j] = (f4v){0.f,0.f,0.f,0.f};

  const int s0 = tid, s1 = tid + 256;
  const int r0 = s0 >> 2, g0 = (s0 & 3) ^ ((r0 >> 1) & 3);
  const int r1 = s1 >> 2, g1 = (s1 & 3) ^ ((r1 >> 1) & 3);
  const int la = l & 15, ch = l >> 4;

  for (int pass = 0; pass < npasses; ++pass){
    const unsigned short* Ap = pass == 0 ? A0 : (pass == 1 ? A1 : A2);
    const unsigned short* Bp = pass == 0 ? B0 : (pass == 1 ? B1 : B2);
    for (int k0 = 0; k0 < K; k0 += 32){
      __syncthreads();
      load_lds16(Ap + (size_t)(m0 + r0)*K + k0 + g0*8, Al + s0*8);
      load_lds16(Ap + (size_t)(m0 + r1)*K + k0 + g1*8, Al + s1*8);
      load_lds16(Bp + (size_t)(n0 + r0)*K + k0 + g0*8, Bl + s0*8);
      load_lds16(Bp + (size_t)(n0 + r1)*K + k0 + g1*8, Bl + s1*8);
      __syncthreads();
      s8v av[4], bv[4];
      #pragma unroll
      for (int mi = 0; mi < 4; ++mi){
        int row = wr*64 + mi*16 + la;
        int cs = ch ^ ((row >> 1) & 3);
        av[mi] = *(const s8v*)(Al + (row*4 + cs)*8);
      }
      #pragma unroll
      for (int ni = 0; ni < 4; ++ni){
        int row = wc*64 + ni*16 + la;
        int cs = ch ^ ((row >> 1) & 3);
        bv[ni] = *(const s8v*)(Bl + (row*4 + cs)*8);
      }
      #pragma unroll
      for (int mi = 0; mi < 4; ++mi)
        #pragma unroll
        for (int ni = 0; ni < 4; ++ni)
          acc[mi][ni] = __builtin_amdgcn_mfma_f32_16x16x32_bf16(av[mi], bv[ni], acc[mi][ni], 0, 0, 0);
    }
  }
  #pragma unroll
  for (int mi = 0; mi < 4; ++mi){
    int row = m0 + wr*64 + mi*16 + (l >> 4)*4;
    #pragma unroll
    for (int ni = 0; ni < 4; ++ni){
      int col = n0 + wc*64 + ni*16 + (l & 15);
      float bb = bias ? bias[col] : 0.0f;
      #pragma unroll
      for (int r = 0; r < 4; ++r)
        Cc[(size_t)(row + r)*N + col] = acc[mi][ni][r] + bb;
    }
  }
}

// ---------------------------------------------------------------------------
// Persistent loop kernel. blk = sub*32 + b (b = blk&31, sub = blk>>5;
// mini group = the 8 subs of batch b, all on one XCD).
// Block owns j-pair {2blk, 2blk+1} x 4 gates for phase D (32KB weights in LDS,
// K=1024: ctx 512 + h 512; emb-part precomputed in gates_emb).
// Per step: A,B | mini | C | arrive-g1 | D-h (hides g1; blk0 then scans) |
//           wait-g1 | D-ctx + update + h-store | arrive-g2 | hall stores
//           (blk0 scans) | wait-g2.
__global__ __launch_bounds__(512, 1) void loop_kernel(
    const float* __restrict__ feats, const float* __restrict__ feat_proj,
    const float* __restrict__ WhT, const float* __restrict__ attn_b,
    const float* __restrict__ v_w,
    const float* __restrict__ W_ih, const float* __restrict__ W_hh,
    const float* __restrict__ b_ih, const float* __restrict__ b_hh,
    const float* __restrict__ gates_emb,
    float* __restrict__ hgrp,          // [T+1][B][512]
    const float* __restrict__ c_init,
    float* __restrict__ ctxbuf,        // [T][B][512]
    float* __restrict__ sps,           // [T][B][200][8]
    unsigned short* __restrict__ hall_h, unsigned short* __restrict__ hall_l,
    unsigned* __restrict__ fm1, unsigned* __restrict__ fg1, unsigned* __restrict__ fg2,
    unsigned* __restrict__ gd1, unsigned* __restrict__ gd2)
{
  __shared__ float Wl[8][1032];    // 33KB: row c -> [Wih ctx-half (512) | Whh (512)]
  __shared__ float red[16*264];    // 16.9KB phase-D reduction
  __shared__ float hs[512];
  __shared__ float hwl[64];
  __shared__ float partA[8][72];
  __shared__ float aux[256];
  __shared__ float bias8[8];
  __shared__ float smx, sinv;

  const int blk = blockIdx.x, tid = threadIdx.x;
  const int b = blk & 31, sub = blk >> 5;
  const int jb = blk*2;
  const int l = tid & 63, wv = tid >> 6;

  // ---- prologue ----
  #pragma unroll
  for (int r = 0; r < 8; ++r){
    const int col = (r >> 1)*512 + jb + (r & 1);
    const float4* wi = (const float4*)(W_ih + (size_t)col*1024 + 512);
    const float4* wh = (const float4*)(W_hh + (size_t)col*512);
    float4* d0 = (float4*)&Wl[r][0];
    float4* d1 = (float4*)&Wl[r][512];
    for (int q = tid; q < 128; q += NT) d0[q] = wi[q];
    for (int q = tid; q < 128; q += NT) d1[q] = wh[q];
  }
  float wreg[64];
  #pragma unroll
  for (int kk = 0; kk < 64; ++kk)
    wreg[kk] = WhT[(size_t)(wv*64 + kk)*512 + sub*64 + l];
  float fpreg[25];
  #pragma unroll
  for (int i = 0; i < 25; ++i){
    const int p = wv + i*8;
    fpreg[i] = (p < P) ? feat_proj[((size_t)b*P + p)*512 + sub*64 + l] : 0.f;
  }
  if (tid < 8){
    const int col = (tid >> 1)*512 + jb + (tid & 1);
    bias8[tid] = b_ih[col] + b_hh[col];
  }
  const float vl = v_w[sub*64 + l];
  const float ab = (tid < 64) ? attn_b[sub*64 + tid] : 0.f;
  float c_reg = 0.f;               // tid<64 owns (bb=tid>>1, jj=tid&1)
  if (tid < 64) c_reg = c_init[(tid >> 1)*512 + jb + (tid & 1)];

  // phase-D decomposition (constant per thread)
  const int kseg = tid >> 5;               // 16 K-segments of 32
  const int bq   = (tid & 31) >> 2;        // 8 batch-quads
  const int cp   = tid & 3;                // 4 col-pairs
  __syncthreads();

  for (int t = 0; t < T; ++t){
    const unsigned gen = (unsigned)(t + 1);

    // ---- A: hWh[b][sub*64..+64) (register WhT slice x LDS-broadcast h) ----
    hs[tid] = hgrp[((size_t)t*B + b)*512 + tid];
    __syncthreads();
    {
      const float* hk = hs + wv*64;
      float a = 0.f;
      #pragma unroll
      for (int kk = 0; kk < 64; ++kk) a += hk[kk] * wreg[kk];
      partA[wv][l] = a;
    }
    __syncthreads();
    if (tid < 64){
      float s = ab;
      #pragma unroll
      for (int k = 0; k < 8; ++k) s += partA[k][tid];
      hwl[tid] = s;
    }
    __syncthreads();

    // ---- B: partial scores over own j-slice (feat_proj from registers) ----
    {
      const float hj = hwl[l];
      float* spw = sps + ((size_t)(t*B + b)*200)*8 + sub;
      #pragma unroll
      for (int i = 0; i < 25; ++i){
        const int p = wv + i*8;
        if (p >= P) break;
        float e2 = vl * fast_tanh(fpreg[i] + hj);
        #pragma unroll
        for (int off = 32; off; off >>= 1) e2 += __shfl_xor(e2, off);
        if (l == 0) cohstore(spw + p*8, e2);
      }
    }
    bar_mini(fm1 + b*8 + sub, fm1 + b*8, gen);

    // ---- C: reduce partials -> softmax -> ctx slice ----
    {
      float sc_v = -1e30f;
      if (tid < P){
        const float* sp = sps + ((size_t)(t*B + b)*200 + tid)*8;
        float4 q0 = *(const float4*)sp, q1 = *(const float4*)(sp + 4);
        sc_v = (q0.x + q0.y + q0.z + q0.w) + (q1.x + q1.y + q1.z + q1.w);
      }
      if (tid < 256) aux[tid] = sc_v;
      __syncthreads();
      if (tid < 64){
        float m = -1e30f;
        #pragma unroll
        for (int i = 0; i < 4; ++i) m = fmaxf(m, aux[tid + i*64]);
        #pragma unroll
        for (int off = 32; off; off >>= 1) m = fmaxf(m, __shfl_xor(m, off));
        if (tid == 0) smx = m;
      }
      __syncthreads();
      float al = (tid < P) ? __expf(sc_v - smx) : 0.f;
      if (tid < 256) aux[tid] = al;
      __syncthreads();
      if (tid < 64){
        float s = 0.f;
        #pragma unroll
        for (int i = 0; i < 4; ++i) s += aux[tid + i*64];
        #pragma unroll
        for (int off = 32; off; off >>= 1) s += __shfl_xor(s, off);
        if (tid == 0) sinv = 1.0f/s;
      }
      __syncthreads();
      float a = 0.f;
      for (int p = wv; p < P; p += 8)
        a += aux[p] * feats[((size_t)b*P + p)*512 + sub*64 + l];
      partA[wv][l] = a;
      __syncthreads();
      if (tid < 64){
        float s = 0.f;
        #pragma unroll
        for (int k = 0; k < 8; ++k) s += partA[k][tid];
        cohstore(ctxbuf + ((size_t)t*B + b)*512 + sub*64 + tid, s * sinv);
      }
    }
    gbar_arrive(fg1, gen);

    // ---- D h-part: inside the grid1 window (h known since step start) ----
    float a0[4], a1[4];
    #pragma unroll
    for (int u = 0; u < 4; ++u){ a0[u] = 0.f; a1[u] = 0.f; }
    {
      const float4* w0 = (const float4*)&Wl[cp*2][512 + kseg*32];
      const float4* w1 = (const float4*)&Wl[cp*2 + 1][512 + kseg*32];
      const float* xh = hgrp + ((size_t)t*B + bq*4)*512 + kseg*32;
      #pragma unroll
      for (int i = 0; i < 8; ++i){
        const float4 wa = w0[i], wb = w1[i];
        #pragma unroll
        for (int u = 0; u < 4; ++u){
          const float4 xv = *(const float4*)(xh + (size_t)u*512 + i*4);
          a0[u] += dot4(wa, xv);
          a1[u] += dot4(wb, xv);
        }
      }
    }
    if (blk == 0) scan_publish(fg1, gd1, gen);
    gbar_wait(gd1, gen);

    // ---- D ctx-part + LSTM update ----
    {
      const float4* w0 = (const float4*)&Wl[cp*2][kseg*32];
      const float4* w1 = (const float4*)&Wl[cp*2 + 1][kseg*32];
      const float* xc = ctxbuf + ((size_t)t*B + bq*4)*512 + kseg*32;
      #pragma unroll
      for (int i = 0; i < 8; ++i){
        const float4 wa = w0[i], wb = w1[i];
        #pragma unroll
        for (int u = 0; u < 4; ++u){
          const float4 xv = *(const float4*)(xc + (size_t)u*512 + i*4);
          a0[u] += dot4(wa, xv);
          a1[u] += dot4(wb, xv);
        }
      }
      #pragma unroll
      for (int u = 0; u < 4; ++u)
        *(float2*)&red[kseg*264 + (bq*4 + u)*8 + cp*2] = make_float2(a0[u], a1[u]);
    }
    __syncthreads();
    unsigned short sh_hh = 0, sh_hl = 0;
    if (tid < 64){
      const int bb = tid >> 1, jj = tid & 1;
      const float* ge = gates_emb + ((size_t)bb*T + t)*2048;
      float gv[4];
      #pragma unroll
      for (int g = 0; g < 4; ++g){
        const int c = g*2 + jj;
        float s = bias8[c] + ge[g*512 + jb + jj];
        #pragma unroll
        for (int k = 0; k < 16; ++k) s += red[k*264 + bb*8 + c];
        gv[g] = s;
      }
      const float i_ = sigmoidf_(gv[0]);
      const float f_ = sigmoidf_(gv[1]);
      const float g_ = fast_tanh(gv[2]);
      const float o_ = sigmoidf_(gv[3]);
      const float c_new = f_*c_reg + i_*g_;
      const float h_new = o_*fast_tanh(c_new);
      c_reg = c_new;
      cohstore(hgrp + ((size_t)(t+1)*B + bb)*512 + jb + jj, h_new);
      sh_hh = f_to_bf16(h_new);
      sh_hl = f_to_bf16(h_new - bf16_to_f(sh_hh));
    }
    gbar_arrive(fg2, gen);
    if (tid < 64){
      const int bb = tid >> 1, jj = tid & 1;
      hall_h[((size_t)bb*T + t)*512 + jb + jj] = sh_hh;
      hall_l[((size_t)bb*T + t)*512 + jb + jj] = sh_hl;
    }
    if (blk == 0) scan_publish(fg2, gd2, gen);
    gbar_wait(gd2, gen);
  }
}

// ---------------------------------------------------------------------------
extern "C" void kernel_launch(void* const* d_in, const int* in_sizes, int n_in,
                              void* d_out, int out_size, void* d_ws, size_t ws_size,
                              hipStream_t stream)
{
  (void)in_sizes; (void)n_in; (void)out_size;
  const float* features = (const float*)d_in[0];
  const int*   captions = (const int*)d_in[1];
  const float* embed_W  = (const float*)d_in[2];
  const float* attn_W   = (const float*)d_in[3];
  const float* attn_b   = (const float*)d_in[4];
  const float* v_w      = (const float*)d_in[5];
  const float* W_ih     = (const float*)d_in[6];
  const float* W_hh     = (const float*)d_in[7];
  const float* b_ih     = (const float*)d_in[8];
  const float* b_hh     = (const float*)d_in[9];
  const float* lin_W    = (const float*)d_in[10];
  const float* lin_b    = (const float*)d_in[11];
  const float* inith_W  = (const float*)d_in[12];
  const float* inith_b  = (const float*)d_in[13];
  const float* initc_W  = (const float*)d_in[14];
  const float* initc_b  = (const float*)d_in[15];

  // "early" scratch in d_out (131MB; all dead before final logits GEMM)
  char* o = (char*)d_out;
  unsigned short* feat_bf   = (unsigned short*)o; o += (size_t)(B*P)*E*2;   // 6.4MB
  unsigned short* Wf_bf     = (unsigned short*)o; o += (size_t)H*E*2;       // 0.5MB
  float*          feat_proj = (float*)o;          o += (size_t)(B*P)*H*4;   // 12.9MB
  unsigned short* emb_hi    = (unsigned short*)o; o += (size_t)(B*T)*E*2;   // 1.05MB
  unsigned short* emb_lo    = (unsigned short*)o; o += (size_t)(B*T)*E*2;
  unsigned short* Wihe_hi   = (unsigned short*)o; o += (size_t)2048*512*2;  // 2.1MB
  unsigned short* Wihe_lo   = (unsigned short*)o; o += (size_t)2048*512*2;
  float*          gates_emb = (float*)o;          o += (size_t)(B*T)*2048*4;// 8.4MB

  // persistent scratch in d_ws
  const size_t SZ_LIN  = (size_t)V*H*2;               // 32.77MB
  const size_t SZ_HALL = (size_t)(B*T)*H*2;           // 1MB
  const size_t SZ_CTX  = (size_t)T*B*512*4;           // 2.1MB
  const size_t SZ_HG   = (size_t)(T+1)*B*512*4;       // 2.16MB
  const size_t SZ_SPS  = (size_t)T*B*200*8*4;         // 6.55MB
  const size_t SZ_ST   = (size_t)B*H*4;               // 64KB
  const size_t SZ_WHT  = (size_t)H*H*4;               // 1MB
  const size_t SZ_FLG  = 4096;
  const size_t need_wo = SZ_LIN + 2*SZ_HALL + SZ_CTX + SZ_HG + SZ_SPS + SZ_ST + SZ_WHT + SZ_FLG;
  const bool three = (ws_size >= need_wo + SZ_LIN);

  char* w = (char*)d_ws;
  unsigned short* lin_hi  = (unsigned short*)w; w += SZ_LIN;
  unsigned short* lin_lo  = (unsigned short*)w; if (three) w += SZ_LIN;
  unsigned short* hall_hi = (unsigned short*)w; w += SZ_HALL;
  unsigned short* hall_lo = (unsigned short*)w; w += SZ_HALL;
  float*          ctxbuf  = (float*)w;          w += SZ_CTX;
  float*          hgrp    = (float*)w;          w += SZ_HG;
  float*          sps     = (float*)w;          w += SZ_SPS;
  float*          c_state = (float*)w;          w += SZ_ST;
  float*          WhT_ws  = (float*)w;          w += SZ_WHT;
  unsigned*       flags   = (unsigned*)w;       w += SZ_FLG;
  unsigned* fm1 = flags;           // [256] mini flags [b*8+sub]
  unsigned* fg1 = flags + 256;     // [256] grid 1 arrival
  unsigned* fg2 = flags + 512;     // [256] grid 2 arrival
  unsigned* gd1 = flags + 768;     // [1] grid 1 done
  unsigned* gd2 = flags + 800;     // [1] grid 2 done (separate line)

  // --- conversions / gathers / init ---
  split_kernel<<<2048, 256, 0, stream>>>(features, E, 0, B*P, feat_bf, nullptr, E, 0);
  split_kernel<<<256, 256, 0, stream>>>(attn_W, E+H, 0, H, Wf_bf, nullptr, E, 0);
  split_kernel<<<2048, 256, 0, stream>>>(lin_W, 512, 0, V, lin_hi, three ? lin_lo : nullptr, 512, 0);
  split_kernel<<<1024, 256, 0, stream>>>(W_ih, 1024, 0, 2048, Wihe_hi, Wihe_lo, 512, 0);
  embed_kernel<<<B*T, 256, 0, stream>>>(captions, embed_W, emb_hi, emb_lo);
  prep_kernel<<<B, 512, 0, stream>>>(features, inith_W, inith_b, initc_W, initc_b,
                                     hgrp, c_state);
  transpose_wh_kernel<<<64, 256, 0, stream>>>(attn_W, WhT_ws);
  hipMemsetAsync(flags, 0, SZ_FLG, stream);

  // feat_proj = features @ Wf^T (bf16 1-pass; error damped through tanh/softmax)
  gemm_bt_kernel<<<(B*P/128)*(E/128), 256, 0, stream>>>(
      feat_bf, feat_bf, feat_bf, Wf_bf, Wf_bf, Wf_bf,
      feat_proj, nullptr, E, E, 1, B*P/128, 0);
  // gates_emb = emb @ W_ih[:, :512]^T (bf16x3)
  gemm_bt_kernel<<<(B*T/128)*(2048/128), 256, 0, stream>>>(
      emb_hi, emb_lo, emb_hi, Wihe_hi, Wihe_hi, Wihe_lo,
      gates_emb, nullptr, 2048, 512, 3, B*T/128, 1);

  // --- recurrence: one persistent kernel, 256 blocks, block 0 scans inline ---
  loop_kernel<<<NB, NT, 0, stream>>>(
      features, feat_proj, WhT_ws, attn_b, v_w, W_ih, W_hh, b_ih, b_hh,
      gates_emb, hgrp, c_state, ctxbuf, sps, hall_hi, hall_lo,
      fm1, fg1, fg2, gd1, gd2);

  // --- logits = h_all @ lin_W^T + lin_b (bf16x3, XCD-swizzled grid) ---
  gemm_bt_kernel<<<(V/128)*(B*T/128), 256, 0, stream>>>(
      hall_hi, hall_lo, hall_hi, lin_hi, lin_hi, three ? lin_lo : lin_hi,
      (float*)d_out, lin_b, V, H, three ? 3 : 2, B*T/128, 1);
}

// Round 15
// 2038.628 us; speedup vs baseline: 1.0378x; 1.0075x over previous
//
// CaptionDecoder on MI355X — round 15: r14 with scan-BEFORE-hidden-work fix.
// r14 bug: block 0 scanned the grid-barrier flags AFTER its D-h work, delaying
// every barrier release by ~3us (x2/step); longer waits also exploded UC poll
// FETCH (961MB). Fix: block0 scans+publishes immediately on arrival, THEN does
// its D-h; gates_emb prefetched into regs at step start; gd polls s_sleep(4).
#include <hip/hip_runtime.h>

#define E 512
#define H 512
#define V 32000
#define B 32
#define P 196
#define T 32
#define NB 256
#define NT 512

typedef __attribute__((ext_vector_type(8))) short s8v;    // 8 bf16
typedef __attribute__((ext_vector_type(4))) float f4v;    // 4 f32 acc

__device__ __forceinline__ float bf16_to_f(unsigned short u){
  return __uint_as_float(((unsigned)u) << 16);
}
__device__ __forceinline__ unsigned short f_to_bf16(float f){
  unsigned u = __float_as_uint(f);
  u += 0x7FFFu + ((u >> 16) & 1u);   // RNE
  return (unsigned short)(u >> 16);
}
__device__ __forceinline__ float fast_tanh(float x){
  float e = __expf(2.0f*x);
  return 1.0f - 2.0f/(e + 1.0f);
}
__device__ __forceinline__ float sigmoidf_(float x){
  return 1.0f/(1.0f + __expf(-x));
}
__device__ __forceinline__ void load_lds16(const unsigned short* g, unsigned short* l){
  __builtin_amdgcn_global_load_lds(
      (const __attribute__((address_space(1))) void*)g,
      (__attribute__((address_space(3))) void*)l, 16, 0, 0);
}
__device__ __forceinline__ float dot4(float4 a, float4 b){
  return a.x*b.x + a.y*b.y + a.z*b.z + a.w*b.w;
}

#define AT_SCOPE __HIP_MEMORY_SCOPE_AGENT
__device__ __forceinline__ void cohstore(float* p, float v){
  __hip_atomic_store(p, v, __ATOMIC_RELAXED, AT_SCOPE);
}
__device__ __forceinline__ unsigned cohldu(const unsigned* p){
  return __hip_atomic_load(p, __ATOMIC_RELAXED, AT_SCOPE);
}
__device__ __forceinline__ void cohstu(unsigned* p, unsigned v){
  __hip_atomic_store(p, v, __ATOMIC_RELAXED, AT_SCOPE);
}

// 8-block mini-barrier (XCD-local group), all relaxed (r9-proven ordering:
// __syncthreads drains vmcnt -> block's coherent stores complete before flag).
__device__ __forceinline__ void bar_mini(unsigned* my, const unsigned* base,
                                         unsigned gen){
  __syncthreads();
  if (threadIdx.x == 0) cohstu(my, gen);
  if (threadIdx.x < 64){
    for (;;){
      unsigned mn = 0xffffffffu;
      for (int i = (int)threadIdx.x; i < 8; i += 64){
        unsigned v = cohldu(base + i);
        mn = v < mn ? v : mn;
      }
      #pragma unroll
      for (int off = 32; off; off >>= 1){
        unsigned o2 = (unsigned)__shfl_xor((int)mn, off);
        mn = o2 < mn ? o2 : mn;
      }
      if (mn >= gen) break;
      __builtin_amdgcn_s_sleep(2);
    }
    __builtin_amdgcn_sched_barrier(0);
  }
  __syncthreads();
}

// Grid barrier pieces: arrive publishes own flag; block 0 scans IMMEDIATELY
// after its arrival and publishes gd; wait polls only gd (backoff sleep 4).
__device__ __forceinline__ void gbar_arrive(unsigned* flags, unsigned gen){
  __syncthreads();
  if (threadIdx.x == 0) cohstu(flags + blockIdx.x, gen);
}
__device__ __forceinline__ void scan_publish(const unsigned* flags, unsigned* gd,
                                             unsigned gen){
  if (threadIdx.x < 64){
    for (;;){
      unsigned mn = 0xffffffffu;
      #pragma unroll
      for (int i = 0; i < 4; ++i){
        unsigned v = cohldu(flags + threadIdx.x + i*64);
        mn = v < mn ? v : mn;
      }
      #pragma unroll
      for (int off = 32; off; off >>= 1){
        unsigned o2 = (unsigned)__shfl_xor((int)mn, off);
        mn = o2 < mn ? o2 : mn;
      }
      if (mn >= gen) break;
      __builtin_amdgcn_s_sleep(1);
    }
    if (threadIdx.x == 0) cohstu(gd, gen);
  }
}
__device__ __forceinline__ void gbar_wait(const unsigned* gd, unsigned gen){
  if (threadIdx.x == 0){
    while (cohldu(gd) < gen) __builtin_amdgcn_s_sleep(4);
    __builtin_amdgcn_sched_barrier(0);
  }
  __syncthreads();
}

// ---------------------------------------------------------------------------
// f32 (strided) -> bf16 hi (+ optional lo residual). cols==512.
__global__ void split_kernel(const float* __restrict__ src, int src_ld, int src_coff,
                             int rows,
                             unsigned short* __restrict__ dhi, unsigned short* __restrict__ dlo,
                             int dst_ld, int dst_coff)
{
  int n = rows << 9;
  for (int i = blockIdx.x*blockDim.x + threadIdx.x; i < n; i += gridDim.x*blockDim.x){
    int r = i >> 9, c = i & 511;
    float x = src[(size_t)r*src_ld + src_coff + c];
    unsigned short h = f_to_bf16(x);
    dhi[(size_t)r*dst_ld + dst_coff + c] = h;
    if (dlo) dlo[(size_t)r*dst_ld + dst_coff + c] = f_to_bf16(x - bf16_to_f(h));
  }
}

// Embedding gather -> bf16 hi/lo rows (row = b*T + t)
__global__ void embed_kernel(const int* __restrict__ caps, const float* __restrict__ embW,
                             unsigned short* __restrict__ ehi, unsigned short* __restrict__ elo)
{
  int row = blockIdx.x;
  int cap = caps[row];
  const float* s = embW + (size_t)cap*E;
  for (int e = threadIdx.x; e < E; e += blockDim.x){
    float x = s[e];
    unsigned short h = f_to_bf16(x);
    ehi[(size_t)row*E + e] = h;
    elo[(size_t)row*E + e] = f_to_bf16(x - bf16_to_f(h));
  }
}

// mean over P, then h0 -> hgrp[0][b], c0 -> c_state
__global__ __launch_bounds__(512) void prep_kernel(
    const float* __restrict__ feats,
    const float* __restrict__ inith_W, const float* __restrict__ inith_b,
    const float* __restrict__ initc_W, const float* __restrict__ initc_b,
    float* __restrict__ hgrp, float* __restrict__ c_state)
{
  __shared__ float mf[E];
  const int b = blockIdx.x, tid = threadIdx.x;
  const float* fb = feats + (size_t)b*P*E + tid;
  float s = 0.f;
  for (int p = 0; p < P; ++p) s += fb[(size_t)p*E];
  mf[tid] = s * (1.0f/196.0f);
  __syncthreads();
  const float* wh = inith_W + (size_t)tid*E;
  const float* wc = initc_W + (size_t)tid*E;
  float h0 = inith_b[tid], c0 = initc_b[tid];
  #pragma unroll 4
  for (int e = 0; e < E; e += 4){
    float4 a4 = *(const float4*)(wh + e);
    float4 b4 = *(const float4*)(wc + e);
    float4 m4 = *(const float4*)(mf + e);
    h0 += dot4(a4, m4);
    c0 += dot4(b4, m4);
  }
  hgrp[(size_t)b*512 + tid] = h0;
  c_state[b*512 + tid] = c0;
}

// WhT[k][j] = attn_W[j][E + k]
__global__ __launch_bounds__(256) void transpose_wh_kernel(
    const float* __restrict__ attn_W, float* __restrict__ WhT)
{
  __shared__ float tile[64][65];
  const int jt = blockIdx.x & 7, kt = blockIdx.x >> 3;
  const int tx = threadIdx.x & 63, ty = threadIdx.x >> 6;
  for (int r = ty; r < 64; r += 4)
    tile[r][tx] = attn_W[(size_t)(jt*64 + r)*(E+H) + E + kt*64 + tx];
  __syncthreads();
  for (int r = ty; r < 64; r += 4)
    WhT[(size_t)(kt*64 + r)*512 + jt*64 + tx] = tile[tx][r];
}

// ---------------------------------------------------------------------------
// m97-style bf16 GEMM: C = sum_passes A_p (MxK) * B_p(NxK)^T [+bias]
__global__ __launch_bounds__(256) void gemm_bt_kernel(
    const unsigned short* __restrict__ A0, const unsigned short* __restrict__ A1,
    const unsigned short* __restrict__ A2,
    const unsigned short* __restrict__ B0, const unsigned short* __restrict__ B1,
    const unsigned short* __restrict__ B2,
    float* __restrict__ Cc, const float* __restrict__ bias,
    int N, int K, int npasses, int mt, int swz)
{
  __shared__ __align__(16) unsigned short Al[128*32];
  __shared__ __align__(16) unsigned short Bl[128*32];
  const int tid = threadIdx.x;
  const int wid = tid >> 6, l = tid & 63;
  int f = blockIdx.x;
  if (swz) f = (f & 7)*((int)gridDim.x >> 3) + (f >> 3);
  const int m0 = (f % mt)*128, n0 = (f / mt)*128;
  const int wr = wid >> 1, wc = wid & 1;

  f4v acc[4][4];
  #pragma unroll
  for (int i = 0; i < 4; ++i)
    #pragma unroll
    for (int j = 0; j < 4; ++j) acc[i][j] = (f4v){0.f,0.f,0.f,0.f};

  const int s0 = tid, s1 = tid + 256;
  const int r0 = s0 >> 2, g0 = (s0 & 3) ^ ((r0 >> 1) & 3);
  const int r1 = s1 >> 2, g1 = (s1 & 3) ^ ((r1 >> 1) & 3);
  const int la = l & 15, ch = l >> 4;

  for (int pass = 0; pass < npasses; ++pass){
    const unsigned short* Ap = pass == 0 ? A0 : (pass == 1 ? A1 : A2);
    const unsigned short* Bp = pass == 0 ? B0 : (pass == 1 ? B1 : B2);
    for (int k0 = 0; k0 < K; k0 += 32){
      __syncthreads();
      load_lds16(Ap + (size_t)(m0 + r0)*K + k0 + g0*8, Al + s0*8);
      load_lds16(Ap + (size_t)(m0 + r1)*K + k0 + g1*8, Al + s1*8);
      load_lds16(Bp + (size_t)(n0 + r0)*K + k0 + g0*8, Bl + s0*8);
      load_lds16(Bp + (size_t)(n0 + r1)*K + k0 + g1*8, Bl + s1*8);
      __syncthreads();
      s8v av[4], bv[4];
      #pragma unroll
      for (int mi = 0; mi < 4; ++mi){
        int row = wr*64 + mi*16 + la;
        int cs = ch ^ ((row >> 1) & 3);
        av[mi] = *(const s8v*)(Al + (row*4 + cs)*8);
      }
      #pragma unroll
      for (int ni = 0; ni < 4; ++ni){
        int row = wc*64 + ni*16 + la;
        int cs = ch ^ ((row >> 1) & 3);
        bv[ni] = *(const s8v*)(Bl + (row*4 + cs)*8);
      }
      #pragma unroll
      for (int mi = 0; mi < 4; ++mi)
        #pragma unroll
        for (int ni = 0; ni < 4; ++ni)
          acc[mi][ni] = __builtin_amdgcn_mfma_f32_16x16x32_bf16(av[mi], bv[ni], acc[mi][ni], 0, 0, 0);
    }
  }
  #pragma unroll
  for (int mi = 0; mi < 4; ++mi){
    int row = m0 + wr*64 + mi*16 + (l >> 4)*4;
    #pragma unroll
    for (int ni = 0; ni < 4; ++ni){
      int col = n0 + wc*64 + ni*16 + (l & 15);
      float bb = bias ? bias[col] : 0.0f;
      #pragma unroll
      for (int r = 0; r < 4; ++r)
        Cc[(size_t)(row + r)*N + col] = acc[mi][ni][r] + bb;
    }
  }
}

// ---------------------------------------------------------------------------
// Persistent loop kernel. blk = sub*32 + b (b = blk&31, sub = blk>>5;
// mini group = the 8 subs of batch b, all on one XCD).
// Block owns j-pair {2blk, 2blk+1} x 4 gates for phase D (32KB weights in LDS,
// K=1024: ctx 512 + h 512; emb-part precomputed in gates_emb, prefetched).
// Per step: [ge prefetch] A,B | mini | C | arrive-g1 (blk0: scan+publish) |
//           D-h (hides g1) | wait-g1 | D-ctx + update + h-store |
//           arrive-g2 (blk0: scan+publish) | hall stores | wait-g2.
__global__ __launch_bounds__(512, 1) void loop_kernel(
    const float* __restrict__ feats, const float* __restrict__ feat_proj,
    const float* __restrict__ WhT, const float* __restrict__ attn_b,
    const float* __restrict__ v_w,
    const float* __restrict__ W_ih, const float* __restrict__ W_hh,
    const float* __restrict__ b_ih, const float* __restrict__ b_hh,
    const float* __restrict__ gates_emb,
    float* __restrict__ hgrp,          // [T+1][B][512]
    const float* __restrict__ c_init,
    float* __restrict__ ctxbuf,        // [T][B][512]
    float* __restrict__ sps,           // [T][B][200][8]
    unsigned short* __restrict__ hall_h, unsigned short* __restrict__ hall_l,
    unsigned* __restrict__ fm1, unsigned* __restrict__ fg1, unsigned* __restrict__ fg2,
    unsigned* __restrict__ gd1, unsigned* __restrict__ gd2)
{
  __shared__ float Wl[8][1032];    // 33KB: row c -> [Wih ctx-half (512) | Whh (512)]
  __shared__ float red[16*264];    // 16.9KB phase-D reduction
  __shared__ float hs[512];
  __shared__ float hwl[64];
  __shared__ float partA[8][72];
  __shared__ float aux[256];
  __shared__ float bias8[8];
  __shared__ float smx, sinv;

  const int blk = blockIdx.x, tid = threadIdx.x;
  const int b = blk & 31, sub = blk >> 5;
  const int jb = blk*2;
  const int l = tid & 63, wv = tid >> 6;

  // ---- prologue ----
  #pragma unroll
  for (int r = 0; r < 8; ++r){
    const int col = (r >> 1)*512 + jb + (r & 1);
    const float4* wi = (const float4*)(W_ih + (size_t)col*1024 + 512);
    const float4* wh = (const float4*)(W_hh + (size_t)col*512);
    float4* d0 = (float4*)&Wl[r][0];
    float4* d1 = (float4*)&Wl[r][512];
    for (int q = tid; q < 128; q += NT) d0[q] = wi[q];
    for (int q = tid; q < 128; q += NT) d1[q] = wh[q];
  }
  float wreg[64];
  #pragma unroll
  for (int kk = 0; kk < 64; ++kk)
    wreg[kk] = WhT[(size_t)(wv*64 + kk)*512 + sub*64 + l];
  float fpreg[25];
  #pragma unroll
  for (int i = 0; i < 25; ++i){
    const int p = wv + i*8;
    fpreg[i] = (p < P) ? feat_proj[((size_t)b*P + p)*512 + sub*64 + l] : 0.f;
  }
  if (tid < 8){
    const int col = (tid >> 1)*512 + jb + (tid & 1);
    bias8[tid] = b_ih[col] + b_hh[col];
  }
  const float vl = v_w[sub*64 + l];
  const float ab = (tid < 64) ? attn_b[sub*64 + tid] : 0.f;
  float c_reg = 0.f;               // tid<64 owns (bb=tid>>1, jj=tid&1)
  if (tid < 64) c_reg = c_init[(tid >> 1)*512 + jb + (tid & 1)];

  // phase-D decomposition (constant per thread)
  const int kseg = tid >> 5;               // 16 K-segments of 32
  const int bq   = (tid & 31) >> 2;        // 8 batch-quads
  const int cp   = tid & 3;                // 4 col-pairs
  __syncthreads();

  for (int t = 0; t < T; ++t){
    const unsigned gen = (unsigned)(t + 1);

    // ---- gates_emb prefetch (scattered L3 reads, hidden under A/B/C) ----
    float gepre[4];
    if (tid < 64){
      const int bb = tid >> 1, jj = tid & 1;
      const float* ge = gates_emb + ((size_t)bb*T + t)*2048;
      #pragma unroll
      for (int g = 0; g < 4; ++g) gepre[g] = ge[g*512 + jb + jj];
    }

    // ---- A: hWh[b][sub*64..+64) (register WhT slice x LDS-broadcast h) ----
    hs[tid] = hgrp[((size_t)t*B + b)*512 + tid];
    __syncthreads();
    {
      const float* hk = hs + wv*64;
      float a = 0.f;
      #pragma unroll
      for (int kk = 0; kk < 64; ++kk) a += hk[kk] * wreg[kk];
      partA[wv][l] = a;
    }
    __syncthreads();
    if (tid < 64){
      float s = ab;
      #pragma unroll
      for (int k = 0; k < 8; ++k) s += partA[k][tid];
      hwl[tid] = s;
    }
    __syncthreads();

    // ---- B: partial scores over own j-slice (feat_proj from registers) ----
    {
      const float hj = hwl[l];
      float* spw = sps + ((size_t)(t*B + b)*200)*8 + sub;
      #pragma unroll
      for (int i = 0; i < 25; ++i){
        const int p = wv + i*8;
        if (p >= P) break;
        float e2 = vl * fast_tanh(fpreg[i] + hj);
        #pragma unroll
        for (int off = 32; off; off >>= 1) e2 += __shfl_xor(e2, off);
        if (l == 0) cohstore(spw + p*8, e2);
      }
    }
    bar_mini(fm1 + b*8 + sub, fm1 + b*8, gen);

    // ---- C: reduce partials -> softmax -> ctx slice ----
    {
      float sc_v = -1e30f;
      if (tid < P){
        const float* sp = sps + ((size_t)(t*B + b)*200 + tid)*8;
        float4 q0 = *(const float4*)sp, q1 = *(const float4*)(sp + 4);
        sc_v = (q0.x + q0.y + q0.z + q0.w) + (q1.x + q1.y + q1.z + q1.w);
      }
      if (tid < 256) aux[tid] = sc_v;
      __syncthreads();
      if (tid < 64){
        float m = -1e30f;
        #pragma unroll
        for (int i = 0; i < 4; ++i) m = fmaxf(m, aux[tid + i*64]);
        #pragma unroll
        for (int off = 32; off; off >>= 1) m = fmaxf(m, __shfl_xor(m, off));
        if (tid == 0) smx = m;
      }
      __syncthreads();
      float al = (tid < P) ? __expf(sc_v - smx) : 0.f;
      if (tid < 256) aux[tid] = al;
      __syncthreads();
      if (tid < 64){
        float s = 0.f;
        #pragma unroll
        for (int i = 0; i < 4; ++i) s += aux[tid + i*64];
        #pragma unroll
        for (int off = 32; off; off >>= 1) s += __shfl_xor(s, off);
        if (tid == 0) sinv = 1.0f/s;
      }
      __syncthreads();
      float a = 0.f;
      for (int p = wv; p < P; p += 8)
        a += aux[p] * feats[((size_t)b*P + p)*512 + sub*64 + l];
      partA[wv][l] = a;
      __syncthreads();
      if (tid < 64){
        float s = 0.f;
        #pragma unroll
        for (int k = 0; k < 8; ++k) s += partA[k][tid];
        cohstore(ctxbuf + ((size_t)t*B + b)*512 + sub*64 + tid, s * sinv);
      }
    }
    gbar_arrive(fg1, gen);
    if (blk == 0) scan_publish(fg1, gd1, gen);   // release FIRST, then hidden work

    // ---- D h-part: inside the grid1 window (h known since step start) ----
    float a0[4], a1[4];
    #pragma unroll
    for (int u = 0; u < 4; ++u){ a0[u] = 0.f; a1[u] = 0.f; }
    {
      const float4* w0 = (const float4*)&Wl[cp*2][512 + kseg*32];
      const float4* w1 = (const float4*)&Wl[cp*2 + 1][512 + kseg*32];
      const float* xh = hgrp + ((size_t)t*B + bq*4)*512 + kseg*32;
      #pragma unroll
      for (int i = 0; i < 8; ++i){
        const float4 wa = w0[i], wb = w1[i];
        #pragma unroll
        for (int u = 0; u < 4; ++u){
          const float4 xv = *(const float4*)(xh + (size_t)u*512 + i*4);
          a0[u] += dot4(wa, xv);
          a1[u] += dot4(wb, xv);
        }
      }
    }
    gbar_wait(gd1, gen);

    // ---- D ctx-part + LSTM update ----
    {
      const float4* w0 = (const float4*)&Wl[cp*2][kseg*32];
      const float4* w1 = (const float4*)&Wl[cp*2 + 1][kseg*32];
      const float* xc = ctxbuf + ((size_t)t*B + bq*4)*512 + kseg*32;
      #pragma unroll
      for (int i = 0; i < 8; ++i){
        const float4 wa = w0[i], wb = w1[i];
        #pragma unroll
        for (int u = 0; u < 4; ++u){
          const float4 xv = *(const float4*)(xc + (size_t)u*512 + i*4);
          a0[u] += dot4(wa, xv);
          a1[u] += dot4(wb, xv);
        }
      }
      #pragma unroll
      for (int u = 0; u < 4; ++u)
        *(float2*)&red[kseg*264 + (bq*4 + u)*8 + cp*2] = make_float2(a0[u], a1[u]);
    }
    __syncthreads();
    unsigned short sh_hh = 0, sh_hl = 0;
    if (tid < 64){
      const int bb = tid >> 1, jj = tid & 1;
      float gv[4];
      #pragma unroll
      for (int g = 0; g < 4; ++g){
        const int c = g*2 + jj;
        float s = bias8[c] + gepre[g];
        #pragma unroll
        for (int k = 0; k < 16; ++k) s += red[k*264 + bb*8 + c];
        gv[g] = s;
      }
      const float i_ = sigmoidf_(gv[0]);
      const float f_ = sigmoidf_(gv[1]);
      const float g_ = fast_tanh(gv[2]);
      const float o_ = sigmoidf_(gv[3]);
      const float c_new = f_*c_reg + i_*g_;
      const float h_new = o_*fast_tanh(c_new);
      c_reg = c_new;
      cohstore(hgrp + ((size_t)(t+1)*B + bb)*512 + jb + jj, h_new);
      sh_hh = f_to_bf16(h_new);
      sh_hl = f_to_bf16(h_new - bf16_to_f(sh_hh));
    }
    gbar_arrive(fg2, gen);
    if (blk == 0) scan_publish(fg2, gd2, gen);   // release FIRST
    if (tid < 64){
      const int bb = tid >> 1, jj = tid & 1;
      hall_h[((size_t)bb*T + t)*512 + jb + jj] = sh_hh;
      hall_l[((size_t)bb*T + t)*512 + jb + jj] = sh_hl;
    }
    gbar_wait(gd2, gen);
  }
}

// ---------------------------------------------------------------------------
extern "C" void kernel_launch(void* const* d_in, const int* in_sizes, int n_in,
                              void* d_out, int out_size, void* d_ws, size_t ws_size,
                              hipStream_t stream)
{
  (void)in_sizes; (void)n_in; (void)out_size;
  const float* features = (const float*)d_in[0];
  const int*   captions = (const int*)d_in[1];
  const float* embed_W  = (const float*)d_in[2];
  const float* attn_W   = (const float*)d_in[3];
  const float* attn_b   = (const float*)d_in[4];
  const float* v_w      = (const float*)d_in[5];
  const float* W_ih     = (const float*)d_in[6];
  const float* W_hh     = (const float*)d_in[7];
  const float* b_ih     = (const float*)d_in[8];
  const float* b_hh     = (const float*)d_in[9];
  const float* lin_W    = (const float*)d_in[10];
  const float* lin_b    = (const float*)d_in[11];
  const float* inith_W  = (const float*)d_in[12];
  const float* inith_b  = (const float*)d_in[13];
  const float* initc_W  = (const float*)d_in[14];
  const float* initc_b  = (const float*)d_in[15];

  // "early" scratch in d_out (131MB; all dead before final logits GEMM)
  char* o = (char*)d_out;
  unsigned short* feat_bf   = (unsigned short*)o; o += (size_t)(B*P)*E*2;   // 6.4MB
  unsigned short* Wf_bf     = (unsigned short*)o; o += (size_t)H*E*2;       // 0.5MB
  float*          feat_proj = (float*)o;          o += (size_t)(B*P)*H*4;   // 12.9MB
  unsigned short* emb_hi    = (unsigned short*)o; o += (size_t)(B*T)*E*2;   // 1.05MB
  unsigned short* emb_lo    = (unsigned short*)o; o += (size_t)(B*T)*E*2;
  unsigned short* Wihe_hi   = (unsigned short*)o; o += (size_t)2048*512*2;  // 2.1MB
  unsigned short* Wihe_lo   = (unsigned short*)o; o += (size_t)2048*512*2;
  float*          gates_emb = (float*)o;          o += (size_t)(B*T)*2048*4;// 8.4MB

  // persistent scratch in d_ws
  const size_t SZ_LIN  = (size_t)V*H*2;               // 32.77MB
  const size_t SZ_HALL = (size_t)(B*T)*H*2;           // 1MB
  const size_t SZ_CTX  = (size_t)T*B*512*4;           // 2.1MB
  const size_t SZ_HG   = (size_t)(T+1)*B*512*4;       // 2.16MB
  const size_t SZ_SPS  = (size_t)T*B*200*8*4;         // 6.55MB
  const size_t SZ_ST   = (size_t)B*H*4;               // 64KB
  const size_t SZ_WHT  = (size_t)H*H*4;               // 1MB
  const size_t SZ_FLG  = 4096;
  const size_t need_wo = SZ_LIN + 2*SZ_HALL + SZ_CTX + SZ_HG + SZ_SPS + SZ_ST + SZ_WHT + SZ_FLG;
  const bool three = (ws_size >= need_wo + SZ_LIN);

  char* w = (char*)d_ws;
  unsigned short* lin_hi  = (unsigned short*)w; w += SZ_LIN;
  unsigned short* lin_lo  = (unsigned short*)w; if (three) w += SZ_LIN;
  unsigned short* hall_hi = (unsigned short*)w; w += SZ_HALL;
  unsigned short* hall_lo = (unsigned short*)w; w += SZ_HALL;
  float*          ctxbuf  = (float*)w;          w += SZ_CTX;
  float*          hgrp    = (float*)w;          w += SZ_HG;
  float*          sps     = (float*)w;          w += SZ_SPS;
  float*          c_state = (float*)w;          w += SZ_ST;
  float*          WhT_ws  = (float*)w;          w += SZ_WHT;
  unsigned*       flags   = (unsigned*)w;       w += SZ_FLG;
  unsigned* fm1 = flags;           // [256] mini flags [b*8+sub]
  unsigned* fg1 = flags + 256;     // [256] grid 1 arrival
  unsigned* fg2 = flags + 512;     // [256] grid 2 arrival
  unsigned* gd1 = flags + 768;     // [1] grid 1 done
  unsigned* gd2 = flags + 800;     // [1] grid 2 done (separate line)

  // --- conversions / gathers / init ---
  split_kernel<<<2048, 256, 0, stream>>>(features, E, 0, B*P, feat_bf, nullptr, E, 0);
  split_kernel<<<256, 256, 0, stream>>>(attn_W, E+H, 0, H, Wf_bf, nullptr, E, 0);
  split_kernel<<<2048, 256, 0, stream>>>(lin_W, 512, 0, V, lin_hi, three ? lin_lo : nullptr, 512, 0);
  split_kernel<<<1024, 256, 0, stream>>>(W_ih, 1024, 0, 2048, Wihe_hi, Wihe_lo, 512, 0);
  embed_kernel<<<B*T, 256, 0, stream>>>(captions, embed_W, emb_hi, emb_lo);
  prep_kernel<<<B, 512, 0, stream>>>(features, inith_W, inith_b, initc_W, initc_b,
                                     hgrp, c_state);
  transpose_wh_kernel<<<64, 256, 0, stream>>>(attn_W, WhT_ws);
  hipMemsetAsync(flags, 0, SZ_FLG, stream);

  // feat_proj = features @ Wf^T (bf16 1-pass; error damped through tanh/softmax)
  gemm_bt_kernel<<<(B*P/128)*(E/128), 256, 0, stream>>>(
      feat_bf, feat_bf, feat_bf, Wf_bf, Wf_bf, Wf_bf,
      feat_proj, nullptr, E, E, 1, B*P/128, 0);
  // gates_emb = emb @ W_ih[:, :512]^T (bf16x3)
  gemm_bt_kernel<<<(B*T/128)*(2048/128), 256, 0, stream>>>(
      emb_hi, emb_lo, emb_hi, Wihe_hi, Wihe_hi, Wihe_lo,
      gates_emb, nullptr, 2048, 512, 3, B*T/128, 1);

  // --- recurrence: one persistent kernel, 256 blocks, block 0 scans inline ---
  loop_kernel<<<NB, NT, 0, stream>>>(
      features, feat_proj, WhT_ws, attn_b, v_w, W_ih, W_hh, b_ih, b_hh,
      gates_emb, hgrp, c_state, ctxbuf, sps, hall_hi, hall_lo,
      fm1, fg1, fg2, gd1, gd2);

  // --- logits = h_all @ lin_W^T + lin_b (bf16x3, XCD-swizzled grid) ---
  gemm_bt_kernel<<<(V/128)*(B*T/128), 256, 0, stream>>>(
      hall_hi, hall_lo, hall_hi, lin_hi, lin_hi, three ? lin_lo : lin_hi,
      (float*)d_out, lin_b, V, H, three ? 3 : 2, B*T/128, 1);
}

// Round 16
// 1612.122 us; speedup vs baseline: 1.3124x; 1.2646x over previous
//
// CaptionDecoder on MI355X — round 16: 2 kernels/step, kernel-boundary sync.
// r11-r15 lesson: hand-rolled cross-XCD grid barriers floor at ~12us; five
// mechanics variants failed to beat it. Pivot: dispatch boundaries ARE grid
// barriers (runtime release/acquire) at graph-replay gap cost, with plain
// memory semantics. Per step: attn_step (hWh+scores+mini8+softmax+ctx) and
// lstm_step (weight-stationary gates K=1024 + LSTM update).
#include <hip/hip_runtime.h>

#define E 512
#define H 512
#define V 32000
#define B 32
#define P 196
#define T 32
#define NT 512

typedef __attribute__((ext_vector_type(8))) short s8v;    // 8 bf16
typedef __attribute__((ext_vector_type(4))) float f4v;    // 4 f32 acc

__device__ __forceinline__ float bf16_to_f(unsigned short u){
  return __uint_as_float(((unsigned)u) << 16);
}
__device__ __forceinline__ unsigned short f_to_bf16(float f){
  unsigned u = __float_as_uint(f);
  u += 0x7FFFu + ((u >> 16) & 1u);   // RNE
  return (unsigned short)(u >> 16);
}
__device__ __forceinline__ float fast_tanh(float x){
  float e = __expf(2.0f*x);
  return 1.0f - 2.0f/(e + 1.0f);
}
__device__ __forceinline__ float sigmoidf_(float x){
  return 1.0f/(1.0f + __expf(-x));
}
__device__ __forceinline__ void load_lds16(const unsigned short* g, unsigned short* l){
  __builtin_amdgcn_global_load_lds(
      (const __attribute__((address_space(1))) void*)g,
      (__attribute__((address_space(3))) void*)l, 16, 0, 0);
}
__device__ __forceinline__ float dot4(float4 a, float4 b){
  return a.x*b.x + a.y*b.y + a.z*b.z + a.w*b.w;
}

#define AT_SCOPE __HIP_MEMORY_SCOPE_AGENT
__device__ __forceinline__ void cohstore(float* p, float v){
  __hip_atomic_store(p, v, __ATOMIC_RELAXED, AT_SCOPE);
}
__device__ __forceinline__ unsigned cohldu(const unsigned* p){
  return __hip_atomic_load(p, __ATOMIC_RELAXED, AT_SCOPE);
}
__device__ __forceinline__ void cohstu(unsigned* p, unsigned v){
  __hip_atomic_store(p, v, __ATOMIC_RELAXED, AT_SCOPE);
}

// 8-block mini-barrier (XCD-local group), all relaxed (r9/r11-proven).
__device__ __forceinline__ void bar_mini(unsigned* my, const unsigned* base,
                                         unsigned gen){
  __syncthreads();
  if (threadIdx.x == 0) cohstu(my, gen);
  if (threadIdx.x < 64){
    for (;;){
      unsigned mn = 0xffffffffu;
      for (int i = (int)threadIdx.x; i < 8; i += 64){
        unsigned v = cohldu(base + i);
        mn = v < mn ? v : mn;
      }
      #pragma unroll
      for (int off = 32; off; off >>= 1){
        unsigned o2 = (unsigned)__shfl_xor((int)mn, off);
        mn = o2 < mn ? o2 : mn;
      }
      if (mn >= gen) break;
      __builtin_amdgcn_s_sleep(2);
    }
    __builtin_amdgcn_sched_barrier(0);
  }
  __syncthreads();
}

// ---------------------------------------------------------------------------
// f32 (strided) -> bf16 hi (+ optional lo residual). cols==512.
__global__ void split_kernel(const float* __restrict__ src, int src_ld, int src_coff,
                             int rows,
                             unsigned short* __restrict__ dhi, unsigned short* __restrict__ dlo,
                             int dst_ld, int dst_coff)
{
  int n = rows << 9;
  for (int i = blockIdx.x*blockDim.x + threadIdx.x; i < n; i += gridDim.x*blockDim.x){
    int r = i >> 9, c = i & 511;
    float x = src[(size_t)r*src_ld + src_coff + c];
    unsigned short h = f_to_bf16(x);
    dhi[(size_t)r*dst_ld + dst_coff + c] = h;
    if (dlo) dlo[(size_t)r*dst_ld + dst_coff + c] = f_to_bf16(x - bf16_to_f(h));
  }
}

// Embedding gather -> bf16 hi/lo rows (row = b*T + t)
__global__ void embed_kernel(const int* __restrict__ caps, const float* __restrict__ embW,
                             unsigned short* __restrict__ ehi, unsigned short* __restrict__ elo)
{
  int row = blockIdx.x;
  int cap = caps[row];
  const float* s = embW + (size_t)cap*E;
  for (int e = threadIdx.x; e < E; e += blockDim.x){
    float x = s[e];
    unsigned short h = f_to_bf16(x);
    ehi[(size_t)row*E + e] = h;
    elo[(size_t)row*E + e] = f_to_bf16(x - bf16_to_f(h));
  }
}

// mean over P, then h0 -> hgrp[0][b], c0 -> c_state[j][b]
__global__ __launch_bounds__(512) void prep_kernel(
    const float* __restrict__ feats,
    const float* __restrict__ inith_W, const float* __restrict__ inith_b,
    const float* __restrict__ initc_W, const float* __restrict__ initc_b,
    float* __restrict__ hgrp, float* __restrict__ c_state)
{
  __shared__ float mf[E];
  const int b = blockIdx.x, tid = threadIdx.x;
  const float* fb = feats + (size_t)b*P*E + tid;
  float s = 0.f;
  for (int p = 0; p < P; ++p) s += fb[(size_t)p*E];
  mf[tid] = s * (1.0f/196.0f);
  __syncthreads();
  const float* wh = inith_W + (size_t)tid*E;
  const float* wc = initc_W + (size_t)tid*E;
  float h0 = inith_b[tid], c0 = initc_b[tid];
  #pragma unroll 4
  for (int e = 0; e < E; e += 4){
    float4 a4 = *(const float4*)(wh + e);
    float4 b4 = *(const float4*)(wc + e);
    float4 m4 = *(const float4*)(mf + e);
    h0 += dot4(a4, m4);
    c0 += dot4(b4, m4);
  }
  hgrp[(size_t)b*512 + tid] = h0;
  c_state[(size_t)tid*32 + b] = c0;      // [j][b] layout
}

// WhTp[sub][k][jl] = attn_W[(sub*64 + jl)*(E+H) + E + k]  (coalesced pack)
__global__ __launch_bounds__(256) void pack_whtp_kernel(
    const float* __restrict__ attn_W, float* __restrict__ WhTp)
{
  __shared__ float tile[64][65];
  const int sub = blockIdx.x >> 3, kc = (blockIdx.x & 7)*64;
  const int tx = threadIdx.x & 63, ty = threadIdx.x >> 6;
  for (int jl = ty; jl < 64; jl += 4)
    tile[jl][tx] = attn_W[(size_t)(sub*64 + jl)*(E+H) + E + kc + tx];
  __syncthreads();
  for (int kk = ty; kk < 64; kk += 4)
    WhTp[((size_t)sub*512 + kc + kk)*64 + tx] = tile[tx][kk];
}

// geT[t][c][b] = gates_emb[(b*T + t)*2048 + c] + b_ih[c] + b_hh[c]
__global__ __launch_bounds__(256) void transb_kernel(
    const float* __restrict__ ge, const float* __restrict__ bih,
    const float* __restrict__ bhh, float* __restrict__ geT)
{
  __shared__ float tile[32][257];
  const int t = blockIdx.x >> 3, cc0 = (blockIdx.x & 7)*256;
  const int tid = threadIdx.x;
  for (int b = 0; b < 32; ++b)
    tile[b][tid] = ge[((size_t)b*T + t)*2048 + cc0 + tid];
  __syncthreads();
  const int bb = tid & 31, ci = tid >> 5;       // ci 0..7
  for (int i = 0; i < 32; ++i){
    const int c = ci*32 + i;
    geT[((size_t)t*2048 + cc0 + c)*32 + bb] = tile[bb][c] + bih[cc0+c] + bhh[cc0+c];
  }
}

// ---------------------------------------------------------------------------
// m97-style bf16 GEMM: C = sum_passes A_p (MxK) * B_p(NxK)^T [+bias]
__global__ __launch_bounds__(256) void gemm_bt_kernel(
    const unsigned short* __restrict__ A0, const unsigned short* __restrict__ A1,
    const unsigned short* __restrict__ A2,
    const unsigned short* __restrict__ B0, const unsigned short* __restrict__ B1,
    const unsigned short* __restrict__ B2,
    float* __restrict__ Cc, const float* __restrict__ bias,
    int N, int K, int npasses, int mt, int swz)
{
  __shared__ __align__(16) unsigned short Al[128*32];
  __shared__ __align__(16) unsigned short Bl[128*32];
  const int tid = threadIdx.x;
  const int wid = tid >> 6, l = tid & 63;
  int f = blockIdx.x;
  if (swz) f = (f & 7)*((int)gridDim.x >> 3) + (f >> 3);
  const int m0 = (f % mt)*128, n0 = (f / mt)*128;
  const int wr = wid >> 1, wc = wid & 1;

  f4v acc[4][4];
  #pragma unroll
  for (int i = 0; i < 4; ++i)
    #pragma unroll
    for (int j = 0; j < 4; ++j) acc[i][j] = (f4v){0.f,0.f,0.f,0.f};

  const int s0 = tid, s1 = tid + 256;
  const int r0 = s0 >> 2, g0 = (s0 & 3) ^ ((r0 >> 1) & 3);
  const int r1 = s1 >> 2, g1 = (s1 & 3) ^ ((r1 >> 1) & 3);
  const int la = l & 15, ch = l >> 4;

  for (int pass = 0; pass < npasses; ++pass){
    const unsigned short* Ap = pass == 0 ? A0 : (pass == 1 ? A1 : A2);
    const unsigned short* Bp = pass == 0 ? B0 : (pass == 1 ? B1 : B2);
    for (int k0 = 0; k0 < K; k0 += 32){
      __syncthreads();
      load_lds16(Ap + (size_t)(m0 + r0)*K + k0 + g0*8, Al + s0*8);
      load_lds16(Ap + (size_t)(m0 + r1)*K + k0 + g1*8, Al + s1*8);
      load_lds16(Bp + (size_t)(n0 + r0)*K + k0 + g0*8, Bl + s0*8);
      load_lds16(Bp + (size_t)(n0 + r1)*K + k0 + g1*8, Bl + s1*8);
      __syncthreads();
      s8v av[4], bv[4];
      #pragma unroll
      for (int mi = 0; mi < 4; ++mi){
        int row = wr*64 + mi*16 + la;
        int cs = ch ^ ((row >> 1) & 3);
        av[mi] = *(const s8v*)(Al + (row*4 + cs)*8);
      }
      #pragma unroll
      for (int ni = 0; ni < 4; ++ni){
        int row = wc*64 + ni*16 + la;
        int cs = ch ^ ((row >> 1) & 3);
        bv[ni] = *(const s8v*)(Bl + (row*4 + cs)*8);
      }
      #pragma unroll
      for (int mi = 0; mi < 4; ++mi)
        #pragma unroll
        for (int ni = 0; ni < 4; ++ni)
          acc[mi][ni] = __builtin_amdgcn_mfma_f32_16x16x32_bf16(av[mi], bv[ni], acc[mi][ni], 0, 0, 0);
    }
  }
  #pragma unroll
  for (int mi = 0; mi < 4; ++mi){
    int row = m0 + wr*64 + mi*16 + (l >> 4)*4;
    #pragma unroll
    for (int ni = 0; ni < 4; ++ni){
      int col = n0 + wc*64 + ni*16 + (l & 15);
      float bb = bias ? bias[col] : 0.0f;
      #pragma unroll
      for (int r = 0; r < 4; ++r)
        Cc[(size_t)(row + r)*N + col] = acc[mi][ni][r] + bb;
    }
  }
}

// ---------------------------------------------------------------------------
// Per-step kernel 1: attention. blk = sub*32 + b (mini group = 8 subs of
// batch b, same XCD). hWh slice from WhTp (coalesced), partial scores -> sps
// (UC), mini, softmax (redundant x8) + ctx slice (plain store).
__global__ __launch_bounds__(512) void attn_step_kernel(
    const float* __restrict__ feats, const float* __restrict__ feat_proj,
    const float* __restrict__ WhTp, const float* __restrict__ attn_b,
    const float* __restrict__ v_w, const float* __restrict__ h_in,
    float* __restrict__ ctx, float* __restrict__ sps,
    unsigned* __restrict__ fm, unsigned gen)
{
  __shared__ float hs[512];
  __shared__ float hwl[64];
  __shared__ float partA[8][72];
  __shared__ float aux[256];
  __shared__ float smx, sinv;

  const int blk = blockIdx.x, tid = threadIdx.x;
  const int b = blk & 31, sub = blk >> 5;
  const int l = tid & 63, wv = tid >> 6;

  hs[tid] = h_in[(size_t)b*512 + tid];
  __syncthreads();

  // A: hWh[b][sub*64 + l] partial over k in [wv*64, wv*64+64)
  {
    const float* wp = WhTp + ((size_t)sub*512 + wv*64)*64 + l;
    const float* hk = hs + wv*64;
    float a = 0.f;
    #pragma unroll
    for (int kk = 0; kk < 64; ++kk) a += hk[kk] * wp[(size_t)kk*64];
    partA[wv][l] = a;
  }
  __syncthreads();
  if (tid < 64){
    float s = attn_b[sub*64 + tid];
    #pragma unroll
    for (int k = 0; k < 8; ++k) s += partA[k][tid];
    hwl[tid] = s;
  }
  __syncthreads();

  // B: partial scores over own j-slice
  {
    const float vl = v_w[sub*64 + l];
    const float hj = hwl[l];
    float* spw = sps + (size_t)b*1600 + sub;     // [b][p][8]
    for (int p = wv; p < P; p += 8){
      float fp = feat_proj[((size_t)b*P + p)*512 + sub*64 + l];
      float e2 = vl * fast_tanh(fp + hj);
      #pragma unroll
      for (int off = 32; off; off >>= 1) e2 += __shfl_xor(e2, off);
      if (l == 0) cohstore(spw + p*8, e2);
    }
  }
  bar_mini(fm + b*8 + sub, fm + b*8, gen);

  // C: reduce partials -> softmax -> ctx slice
  {
    float sc_v = -1e30f;
    if (tid < P){
      const float* sp = sps + (size_t)b*1600 + tid*8;
      float4 q0 = *(const float4*)sp, q1 = *(const float4*)(sp + 4);
      sc_v = (q0.x + q0.y + q0.z + q0.w) + (q1.x + q1.y + q1.z + q1.w);
    }
    if (tid < 256) aux[tid] = sc_v;
    __syncthreads();
    if (tid < 64){
      float m = -1e30f;
      #pragma unroll
      for (int i = 0; i < 4; ++i) m = fmaxf(m, aux[tid + i*64]);
      #pragma unroll
      for (int off = 32; off; off >>= 1) m = fmaxf(m, __shfl_xor(m, off));
      if (tid == 0) smx = m;
    }
    __syncthreads();
    float al = (tid < P) ? __expf(sc_v - smx) : 0.f;
    if (tid < 256) aux[tid] = al;
    __syncthreads();
    if (tid < 64){
      float s = 0.f;
      #pragma unroll
      for (int i = 0; i < 4; ++i) s += aux[tid + i*64];
      #pragma unroll
      for (int off = 32; off; off >>= 1) s += __shfl_xor(s, off);
      if (tid == 0) sinv = 1.0f/s;
    }
    __syncthreads();
    float a = 0.f;
    for (int p = wv; p < P; p += 8)
      a += aux[p] * feats[((size_t)b*P + p)*512 + sub*64 + l];
    partA[wv][l] = a;
    __syncthreads();
    if (tid < 64){
      float s = 0.f;
      #pragma unroll
      for (int k = 0; k < 8; ++k) s += partA[k][tid];
      ctx[(size_t)b*512 + sub*64 + tid] = s * sinv;   // plain store
    }
  }
}

// ---------------------------------------------------------------------------
// Per-step kernel 2: LSTM gates + update. blk owns j-pair {2blk, 2blk+1}
// x 4 gates; 32KB weight slice staged to LDS; K=1024 (ctx 512 + h 512);
// emb-part+biases pre-folded in geT_t[c][b].
__global__ __launch_bounds__(512) void lstm_step_kernel(
    const float* __restrict__ W_ih, const float* __restrict__ W_hh,
    const float* __restrict__ geT_t,
    const float* __restrict__ ctx, const float* __restrict__ h_in,
    float* __restrict__ h_out, float* __restrict__ c_state,
    unsigned short* __restrict__ hall_h, unsigned short* __restrict__ hall_l,
    int t)
{
  __shared__ float Wl[8][1032];    // row c -> [Wih ctx-half (512) | Whh (512)]
  __shared__ float red[16*264];

  const int blk = blockIdx.x, tid = threadIdx.x;
  const int jb = blk*2;

  #pragma unroll
  for (int r = 0; r < 8; ++r){
    const int col = (r >> 1)*512 + jb + (r & 1);
    const float4* wi = (const float4*)(W_ih + (size_t)col*1024 + 512);
    const float4* wh = (const float4*)(W_hh + (size_t)col*512);
    float4* d0 = (float4*)&Wl[r][0];
    float4* d1 = (float4*)&Wl[r][512];
    for (int q = tid; q < 128; q += NT) d0[q] = wi[q];
    for (int q = tid; q < 128; q += NT) d1[q] = wh[q];
  }
  __syncthreads();

  const int kseg = tid >> 5;               // 16 K-segments of 32
  const int bq   = (tid & 31) >> 2;        // 8 batch-quads
  const int cp   = tid & 3;                // 4 col-pairs

  float a0[4], a1[4];
  #pragma unroll
  for (int u = 0; u < 4; ++u){ a0[u] = 0.f; a1[u] = 0.f; }
  {
    const float4* w0 = (const float4*)&Wl[cp*2][kseg*32];
    const float4* w1 = (const float4*)&Wl[cp*2 + 1][kseg*32];
    const float* xc = ctx + (size_t)(bq*4)*512 + kseg*32;
    #pragma unroll
    for (int i = 0; i < 8; ++i){
      const float4 wa = w0[i], wb = w1[i];
      #pragma unroll
      for (int u = 0; u < 4; ++u){
        const float4 xv = *(const float4*)(xc + (size_t)u*512 + i*4);
        a0[u] += dot4(wa, xv);
        a1[u] += dot4(wb, xv);
      }
    }
  }
  {
    const float4* w0 = (const float4*)&Wl[cp*2][512 + kseg*32];
    const float4* w1 = (const float4*)&Wl[cp*2 + 1][512 + kseg*32];
    const float* xh = h_in + (size_t)(bq*4)*512 + kseg*32;
    #pragma unroll
    for (int i = 0; i < 8; ++i){
      const float4 wa = w0[i], wb = w1[i];
      #pragma unroll
      for (int u = 0; u < 4; ++u){
        const float4 xv = *(const float4*)(xh + (size_t)u*512 + i*4);
        a0[u] += dot4(wa, xv);
        a1[u] += dot4(wb, xv);
      }
    }
  }
  #pragma unroll
  for (int u = 0; u < 4; ++u)
    *(float2*)&red[kseg*264 + (bq*4 + u)*8 + cp*2] = make_float2(a0[u], a1[u]);
  __syncthreads();

  if (tid < 64){
    const int bb = tid >> 1, jj = tid & 1;
    float gv[4];
    #pragma unroll
    for (int g = 0; g < 4; ++g){
      const int c = g*2 + jj;
      float s = geT_t[((size_t)g*512 + jb + jj)*32 + bb];
      #pragma unroll
      for (int k = 0; k < 16; ++k) s += red[k*264 + bb*8 + c];
      gv[g] = s;
    }
    const float i_ = sigmoidf_(gv[0]);
    const float f_ = sigmoidf_(gv[1]);
    const float g_ = fast_tanh(gv[2]);
    const float o_ = sigmoidf_(gv[3]);
    const size_t cidx = (size_t)(jb + jj)*32 + bb;       // [j][b]
    const float c_new = f_*c_state[cidx] + i_*g_;
    const float h_new = o_*fast_tanh(c_new);
    c_state[cidx] = c_new;
    h_out[(size_t)bb*512 + jb + jj] = h_new;
    const unsigned short hh = f_to_bf16(h_new);
    hall_h[((size_t)bb*T + t)*512 + jb + jj] = hh;
    hall_l[((size_t)bb*T + t)*512 + jb + jj] = f_to_bf16(h_new - bf16_to_f(hh));
  }
}

// ---------------------------------------------------------------------------
extern "C" void kernel_launch(void* const* d_in, const int* in_sizes, int n_in,
                              void* d_out, int out_size, void* d_ws, size_t ws_size,
                              hipStream_t stream)
{
  (void)in_sizes; (void)n_in; (void)out_size;
  const float* features = (const float*)d_in[0];
  const int*   captions = (const int*)d_in[1];
  const float* embed_W  = (const float*)d_in[2];
  const float* attn_W   = (const float*)d_in[3];
  const float* attn_b   = (const float*)d_in[4];
  const float* v_w      = (const float*)d_in[5];
  const float* W_ih     = (const float*)d_in[6];
  const float* W_hh     = (const float*)d_in[7];
  const float* b_ih     = (const float*)d_in[8];
  const float* b_hh     = (const float*)d_in[9];
  const float* lin_W    = (const float*)d_in[10];
  const float* lin_b    = (const float*)d_in[11];
  const float* inith_W  = (const float*)d_in[12];
  const float* inith_b  = (const float*)d_in[13];
  const float* initc_W  = (const float*)d_in[14];
  const float* initc_b  = (const float*)d_in[15];

  // "early" scratch in d_out (131MB; all dead before final logits GEMM)
  char* o = (char*)d_out;
  unsigned short* feat_bf   = (unsigned short*)o; o += (size_t)(B*P)*E*2;   // 6.4MB
  unsigned short* Wf_bf     = (unsigned short*)o; o += (size_t)H*E*2;       // 0.5MB
  float*          feat_proj = (float*)o;          o += (size_t)(B*P)*H*4;   // 12.9MB
  unsigned short* emb_hi    = (unsigned short*)o; o += (size_t)(B*T)*E*2;   // 1.05MB
  unsigned short* emb_lo    = (unsigned short*)o; o += (size_t)(B*T)*E*2;
  unsigned short* Wihe_hi   = (unsigned short*)o; o += (size_t)2048*512*2;  // 2.1MB
  unsigned short* Wihe_lo   = (unsigned short*)o; o += (size_t)2048*512*2;
  float*          gates_emb = (float*)o;          o += (size_t)(B*T)*2048*4;// 8.4MB
  float*          geT       = (float*)o;          o += (size_t)T*2048*32*4; // 8.4MB
  float*          WhTp      = (float*)o;          o += (size_t)H*H*4;       // 1MB

  // persistent scratch in d_ws
  const size_t SZ_LIN  = (size_t)V*H*2;               // 32.77MB
  const size_t SZ_HALL = (size_t)(B*T)*H*2;           // 1MB
  const size_t SZ_CTX  = (size_t)B*512*4;             // 64KB
  const size_t SZ_HG   = (size_t)(T+1)*B*512*4;       // 2.16MB
  const size_t SZ_SPS  = (size_t)B*1600*4;            // 204KB
  const size_t SZ_ST   = (size_t)B*H*4;               // 64KB
  const size_t SZ_FLG  = 4096;
  const size_t need_wo = SZ_LIN + 2*SZ_HALL + SZ_CTX + SZ_HG + SZ_SPS + SZ_ST + SZ_FLG;
  const bool three = (ws_size >= need_wo + SZ_LIN);

  char* w = (char*)d_ws;
  unsigned short* lin_hi  = (unsigned short*)w; w += SZ_LIN;
  unsigned short* lin_lo  = (unsigned short*)w; if (three) w += SZ_LIN;
  unsigned short* hall_hi = (unsigned short*)w; w += SZ_HALL;
  unsigned short* hall_lo = (unsigned short*)w; w += SZ_HALL;
  float*          ctx_ws  = (float*)w;          w += SZ_CTX;
  float*          hgrp    = (float*)w;          w += SZ_HG;
  float*          sps     = (float*)w;          w += SZ_SPS;
  float*          c_state = (float*)w;          w += SZ_ST;
  unsigned*       flags   = (unsigned*)w;       w += SZ_FLG;
  unsigned* fm1 = flags;           // [256] mini flags [b*8+sub]

  // --- conversions / packs / init ---
  split_kernel<<<2048, 256, 0, stream>>>(features, E, 0, B*P, feat_bf, nullptr, E, 0);
  split_kernel<<<256, 256, 0, stream>>>(attn_W, E+H, 0, H, Wf_bf, nullptr, E, 0);
  split_kernel<<<2048, 256, 0, stream>>>(lin_W, 512, 0, V, lin_hi, three ? lin_lo : nullptr, 512, 0);
  split_kernel<<<1024, 256, 0, stream>>>(W_ih, 1024, 0, 2048, Wihe_hi, Wihe_lo, 512, 0);
  embed_kernel<<<B*T, 256, 0, stream>>>(captions, embed_W, emb_hi, emb_lo);
  prep_kernel<<<B, 512, 0, stream>>>(features, inith_W, inith_b, initc_W, initc_b,
                                     hgrp, c_state);
  pack_whtp_kernel<<<64, 256, 0, stream>>>(attn_W, WhTp);
  hipMemsetAsync(flags, 0, SZ_FLG, stream);

  // feat_proj = features @ Wf^T (bf16 1-pass; error damped through tanh/softmax)
  gemm_bt_kernel<<<(B*P/128)*(E/128), 256, 0, stream>>>(
      feat_bf, feat_bf, feat_bf, Wf_bf, Wf_bf, Wf_bf,
      feat_proj, nullptr, E, E, 1, B*P/128, 0);
  // gates_emb = emb @ W_ih[:, :512]^T (bf16x3), then transpose + bias fold
  gemm_bt_kernel<<<(B*T/128)*(2048/128), 256, 0, stream>>>(
      emb_hi, emb_lo, emb_hi, Wihe_hi, Wihe_hi, Wihe_lo,
      gates_emb, nullptr, 2048, 512, 3, B*T/128, 1);
  transb_kernel<<<256, 256, 0, stream>>>(gates_emb, b_ih, b_hh, geT);

  // --- recurrence: 2 dispatches per step, kernel-boundary sync ---
  for (int t = 0; t < T; ++t){
    attn_step_kernel<<<256, 512, 0, stream>>>(
        features, feat_proj, WhTp, attn_b, v_w,
        hgrp + (size_t)t*B*512, ctx_ws, sps, fm1, (unsigned)(t + 1));
    lstm_step_kernel<<<256, 512, 0, stream>>>(
        W_ih, W_hh, geT + (size_t)t*2048*32,
        ctx_ws, hgrp + (size_t)t*B*512, hgrp + (size_t)(t+1)*B*512,
        c_state, hall_hi, hall_lo, t);
  }

  // --- logits = h_all @ lin_W^T + lin_b (bf16x3, XCD-swizzled grid) ---
  gemm_bt_kernel<<<(V/128)*(B*T/128), 256, 0, stream>>>(
      hall_hi, hall_lo, hall_hi, lin_hi, lin_hi, three ? lin_lo : lin_hi,
      (float*)d_out, lin_b, V, H, three ? 3 : 2, B*T/128, 1);
}

// Round 17
// 1247.425 us; speedup vs baseline: 1.6961x; 1.2924x over previous
//
// CaptionDecoder on MI355X — round 17: batch-local, zero global sync, L2-resident weights.
// r16 proved dispatch boundaries cost ~16us = same floor as hand barriers.
// Only escape: need NO global sync. Batch chains are independent -> r12's
// batch-local partition, fixed: r12 thrashed L2 (4.2MB/XCD working set).
// Park feat_proj+features slices in REGISTERS -> working set ~1.1MB/XCD ->
// Wpack[sub] (1MB, shared by all 32 same-sub blocks per XCD) stays L2-resident.
// Per step: 3 XCD-cheap 8-block mini-barriers only.
#include <hip/hip_runtime.h>

#define E 512
#define H 512
#define V 32000
#define B 32
#define P 196
#define T 32
#define NB 256
#define NT 512

typedef __attribute__((ext_vector_type(8))) short s8v;    // 8 bf16
typedef __attribute__((ext_vector_type(4))) float f4v;    // 4 f32 acc

__device__ __forceinline__ float bf16_to_f(unsigned short u){
  return __uint_as_float(((unsigned)u) << 16);
}
__device__ __forceinline__ unsigned short f_to_bf16(float f){
  unsigned u = __float_as_uint(f);
  u += 0x7FFFu + ((u >> 16) & 1u);   // RNE
  return (unsigned short)(u >> 16);
}
__device__ __forceinline__ float fast_tanh(float x){
  float e = __expf(2.0f*x);
  return 1.0f - 2.0f/(e + 1.0f);
}
__device__ __forceinline__ float sigmoidf_(float x){
  return 1.0f/(1.0f + __expf(-x));
}
__device__ __forceinline__ void load_lds16(const unsigned short* g, unsigned short* l){
  __builtin_amdgcn_global_load_lds(
      (const __attribute__((address_space(1))) void*)g,
      (__attribute__((address_space(3))) void*)l, 16, 0, 0);
}
__device__ __forceinline__ float dot4(float4 a, float4 b){
  return a.x*b.x + a.y*b.y + a.z*b.z + a.w*b.w;
}

#define AT_SCOPE __HIP_MEMORY_SCOPE_AGENT
__device__ __forceinline__ void cohstore(float* p, float v){
  __hip_atomic_store(p, v, __ATOMIC_RELAXED, AT_SCOPE);
}
__device__ __forceinline__ unsigned cohldu(const unsigned* p){
  return __hip_atomic_load(p, __ATOMIC_RELAXED, AT_SCOPE);
}
__device__ __forceinline__ void cohstu(unsigned* p, unsigned v){
  __hip_atomic_store(p, v, __ATOMIC_RELAXED, AT_SCOPE);
}

// 8-block mini-barrier, split arrive/wait (all relaxed; __syncthreads drains
// vmcnt -> the block's coherent stores are LLC-visible before the flag).
__device__ __forceinline__ void bar_arrive(unsigned* my, unsigned gen){
  __syncthreads();
  if (threadIdx.x == 0) cohstu(my, gen);
}
__device__ __forceinline__ void bar_wait(const unsigned* base, unsigned gen){
  if (threadIdx.x < 64){
    for (;;){
      unsigned mn = 0xffffffffu;
      for (int i = (int)threadIdx.x; i < 8; i += 64){
        unsigned v = cohldu(base + i);
        mn = v < mn ? v : mn;
      }
      #pragma unroll
      for (int off = 32; off; off >>= 1){
        unsigned o2 = (unsigned)__shfl_xor((int)mn, off);
        mn = o2 < mn ? o2 : mn;
      }
      if (mn >= gen) break;
      __builtin_amdgcn_s_sleep(2);
    }
    __builtin_amdgcn_sched_barrier(0);
  }
  __syncthreads();
}
__device__ __forceinline__ void bar_mini(unsigned* my, const unsigned* base,
                                         unsigned gen){
  bar_arrive(my, gen);
  bar_wait(base, gen);
}

// ---------------------------------------------------------------------------
// f32 (strided) -> bf16 hi (+ optional lo residual). cols==512.
__global__ void split_kernel(const float* __restrict__ src, int src_ld, int src_coff,
                             int rows,
                             unsigned short* __restrict__ dhi, unsigned short* __restrict__ dlo,
                             int dst_ld, int dst_coff)
{
  int n = rows << 9;
  for (int i = blockIdx.x*blockDim.x + threadIdx.x; i < n; i += gridDim.x*blockDim.x){
    int r = i >> 9, c = i & 511;
    float x = src[(size_t)r*src_ld + src_coff + c];
    unsigned short h = f_to_bf16(x);
    dhi[(size_t)r*dst_ld + dst_coff + c] = h;
    if (dlo) dlo[(size_t)r*dst_ld + dst_coff + c] = f_to_bf16(x - bf16_to_f(h));
  }
}

// Embedding gather -> bf16 hi/lo rows (row = b*T + t)
__global__ void embed_kernel(const int* __restrict__ caps, const float* __restrict__ embW,
                             unsigned short* __restrict__ ehi, unsigned short* __restrict__ elo)
{
  int row = blockIdx.x;
  int cap = caps[row];
  const float* s = embW + (size_t)cap*E;
  for (int e = threadIdx.x; e < E; e += blockDim.x){
    float x = s[e];
    unsigned short h = f_to_bf16(x);
    ehi[(size_t)row*E + e] = h;
    elo[(size_t)row*E + e] = f_to_bf16(x - bf16_to_f(h));
  }
}

// mean over P, then h0 -> hgrp[0][b], c0 -> c_state
__global__ __launch_bounds__(512) void prep_kernel(
    const float* __restrict__ feats,
    const float* __restrict__ inith_W, const float* __restrict__ inith_b,
    const float* __restrict__ initc_W, const float* __restrict__ initc_b,
    float* __restrict__ hgrp, float* __restrict__ c_state)
{
  __shared__ float mf[E];
  const int b = blockIdx.x, tid = threadIdx.x;
  const float* fb = feats + (size_t)b*P*E + tid;
  float s = 0.f;
  for (int p = 0; p < P; ++p) s += fb[(size_t)p*E];
  mf[tid] = s * (1.0f/196.0f);
  __syncthreads();
  const float* wh = inith_W + (size_t)tid*E;
  const float* wc = initc_W + (size_t)tid*E;
  float h0 = inith_b[tid], c0 = initc_b[tid];
  #pragma unroll 4
  for (int e = 0; e < E; e += 4){
    float4 a4 = *(const float4*)(wh + e);
    float4 b4 = *(const float4*)(wc + e);
    float4 m4 = *(const float4*)(mf + e);
    h0 += dot4(a4, m4);
    c0 += dot4(b4, m4);
  }
  hgrp[(size_t)b*512 + tid] = h0;
  c_state[b*512 + tid] = c0;
}

// WhT[k][j] = attn_W[j][E + k]
__global__ __launch_bounds__(256) void transpose_wh_kernel(
    const float* __restrict__ attn_W, float* __restrict__ WhT)
{
  __shared__ float tile[64][65];
  const int jt = blockIdx.x & 7, kt = blockIdx.x >> 3;
  const int tx = threadIdx.x & 63, ty = threadIdx.x >> 6;
  for (int r = ty; r < 64; r += 4)
    tile[r][tx] = attn_W[(size_t)(jt*64 + r)*(E+H) + E + kt*64 + tx];
  __syncthreads();
  for (int r = ty; r < 64; r += 4)
    WhT[(size_t)(kt*64 + r)*512 + jt*64 + tx] = tile[tx][r];
}

// Wpack[sub][k][c]: k in [0,512) = Wih ctx-half of gate col; [512,1024) = Whh.
// c in [0,256): gcol = (c>>6)*512 + sub*64 + (c&63). Coalesced repack.
__global__ __launch_bounds__(256) void pack_wd_kernel(
    const float* __restrict__ Wih, const float* __restrict__ Whh,
    float* __restrict__ Wpack)
{
  __shared__ float tile[64][65];
  const int sub = blockIdx.x & 7, cg = (blockIdx.x >> 3) & 3, kg = blockIdx.x >> 5;
  const int tx = threadIdx.x & 63, ty = threadIdx.x >> 6;
  const int kbase = kg*64;
  for (int cl = ty; cl < 64; cl += 4){
    const int c = cg*64 + cl;
    const int gcol = (c >> 6)*512 + sub*64 + (c & 63);
    const int k = kbase + tx;
    tile[cl][tx] = (k < 512) ? Wih[(size_t)gcol*1024 + 512 + k]
                             : Whh[(size_t)gcol*512 + k - 512];
  }
  __syncthreads();
  for (int kk = ty; kk < 64; kk += 4)
    Wpack[((size_t)sub*1024 + kbase + kk)*256 + cg*64 + tx] = tile[tx][kk];
}

// ---------------------------------------------------------------------------
// m97-style bf16 GEMM: C = sum_passes A_p (MxK) * B_p(NxK)^T [+bias]
__global__ __launch_bounds__(256) void gemm_bt_kernel(
    const unsigned short* __restrict__ A0, const unsigned short* __restrict__ A1,
    const unsigned short* __restrict__ A2,
    const unsigned short* __restrict__ B0, const unsigned short* __restrict__ B1,
    const unsigned short* __restrict__ B2,
    float* __restrict__ Cc, const float* __restrict__ bias,
    int N, int K, int npasses, int mt, int swz)
{
  __shared__ __align__(16) unsigned short Al[128*32];
  __shared__ __align__(16) unsigned short Bl[128*32];
  const int tid = threadIdx.x;
  const int wid = tid >> 6, l = tid & 63;
  int f = blockIdx.x;
  if (swz) f = (f & 7)*((int)gridDim.x >> 3) + (f >> 3);
  const int m0 = (f % mt)*128, n0 = (f / mt)*128;
  const int wr = wid >> 1, wc = wid & 1;

  f4v acc[4][4];
  #pragma unroll
  for (int i = 0; i < 4; ++i)
    #pragma unroll
    for (int j = 0; j < 4; ++j) acc[i][j] = (f4v){0.f,0.f,0.f,0.f};

  const int s0 = tid, s1 = tid + 256;
  const int r0 = s0 >> 2, g0 = (s0 & 3) ^ ((r0 >> 1) & 3);
  const int r1 = s1 >> 2, g1 = (s1 & 3) ^ ((r1 >> 1) & 3);
  const int la = l & 15, ch = l >> 4;

  for (int pass = 0; pass < npasses; ++pass){
    const unsigned short* Ap = pass == 0 ? A0 : (pass == 1 ? A1 : A2);
    const unsigned short* Bp = pass == 0 ? B0 : (pass == 1 ? B1 : B2);
    for (int k0 = 0; k0 < K; k0 += 32){
      __syncthreads();
      load_lds16(Ap + (size_t)(m0 + r0)*K + k0 + g0*8, Al + s0*8);
      load_lds16(Ap + (size_t)(m0 + r1)*K + k0 + g1*8, Al + s1*8);
      load_lds16(Bp + (size_t)(n0 + r0)*K + k0 + g0*8, Bl + s0*8);
      load_lds16(Bp + (size_t)(n0 + r1)*K + k0 + g1*8, Bl + s1*8);
      __syncthreads();
      s8v av[4], bv[4];
      #pragma unroll
      for (int mi = 0; mi < 4; ++mi){
        int row = wr*64 + mi*16 + la;
        int cs = ch ^ ((row >> 1) & 3);
        av[mi] = *(const s8v*)(Al + (row*4 + cs)*8);
      }
      #pragma unroll
      for (int ni = 0; ni < 4; ++ni){
        int row = wc*64 + ni*16 + la;
        int cs = ch ^ ((row >> 1) & 3);
        bv[ni] = *(const s8v*)(Bl + (row*4 + cs)*8);
      }
      #pragma unroll
      for (int mi = 0; mi < 4; ++mi)
        #pragma unroll
        for (int ni = 0; ni < 4; ++ni)
          acc[mi][ni] = __builtin_amdgcn_mfma_f32_16x16x32_bf16(av[mi], bv[ni], acc[mi][ni], 0, 0, 0);
    }
  }
  #pragma unroll
  for (int mi = 0; mi < 4; ++mi){
    int row = m0 + wr*64 + mi*16 + (l >> 4)*4;
    #pragma unroll
    for (int ni = 0; ni < 4; ++ni){
      int col = n0 + wc*64 + ni*16 + (l & 15);
      float bb = bias ? bias[col] : 0.0f;
      #pragma unroll
      for (int r = 0; r < 4; ++r)
        Cc[(size_t)(row + r)*N + col] = acc[mi][ni][r] + bb;
    }
  }
}

// ---------------------------------------------------------------------------
// Persistent loop kernel, batch-local groups, ZERO global sync.
// blk = b*8 + sub (group = 8 blocks of batch b; same-sub blocks share one XCD
// under mod-8 dispatch -> Wpack[sub] (1MB) is L2-resident per XCD).
// Block owns j-slice sub*64..+64 x 4 gates = 256 gate cols of ITS batch.
// feat_proj & features slices live in REGISTERS (fpreg/ftreg) -> B/C phases
// have no global reads; per-XCD L2 working set ~1.1MB.
// Per step: [A+B] mini1 [C] arrive2 [D-h] wait2 [D-ctx + update] mini3.
__global__ __launch_bounds__(512, 1) void loop_kernel(
    const float* __restrict__ feats, const float* __restrict__ feat_proj,
    const float* __restrict__ WhT, const float* __restrict__ attn_b,
    const float* __restrict__ v_w, const float* __restrict__ Wpack,
    const float* __restrict__ gates_emb,
    const float* __restrict__ b_ih, const float* __restrict__ b_hh,
    float* __restrict__ hgrp,          // [T+1][B][512]
    const float* __restrict__ c_init,
    float* __restrict__ ctxbuf,        // [T][B][512]
    float* __restrict__ sps,           // [T][B][200][8]
    unsigned short* __restrict__ hall_h, unsigned short* __restrict__ hall_l,
    unsigned* __restrict__ fm1, unsigned* __restrict__ fm2, unsigned* __restrict__ fm3)
{
  __shared__ float hs[512];
  __shared__ float ctxl[512];
  __shared__ float hwl[64];
  __shared__ float partA[8][72];
  __shared__ float aux[256];
  __shared__ float biasl[256];
  __shared__ float red[512];
  __shared__ float smx, sinv;

  const int blk = blockIdx.x, tid = threadIdx.x;
  const int b = blk >> 3, sub = blk & 7;
  const int gbase = blk & ~7;
  const int l = tid & 63, wv = tid >> 6;

  // ---- prologue: registers + small LDS ----
  float wreg[64];
  #pragma unroll
  for (int kk = 0; kk < 64; ++kk)
    wreg[kk] = WhT[(size_t)(wv*64 + kk)*512 + sub*64 + l];
  float fpreg[25], ftreg[25];
  #pragma unroll
  for (int i = 0; i < 25; ++i){
    const int p = wv + i*8;
    const size_t g = ((size_t)b*P + (p < P ? p : 0))*512 + sub*64 + l;
    fpreg[i] = (p < P) ? feat_proj[g] : 0.f;
    ftreg[i] = (p < P) ? feats[g] : 0.f;
  }
  for (int c = tid; c < 256; c += NT){
    const int gcol = (c >> 6)*512 + sub*64 + (c & 63);
    biasl[c] = b_ih[gcol] + b_hh[gcol];
  }
  const float vl = v_w[sub*64 + l];
  const float ab = (tid < 64) ? attn_b[sub*64 + tid] : 0.f;
  float c_reg = 0.f;
  if (tid < 64) c_reg = c_init[b*512 + sub*64 + tid];

  // phase-D decomposition: thread = (dc: block-local col, kh: K half)
  const int dc = tid & 255;
  const int kh = tid >> 8;
  const float* wp_h = Wpack + ((size_t)sub*1024 + 512 + kh*256)*256 + dc;
  const float* wp_c = Wpack + ((size_t)sub*1024 +       kh*256)*256 + dc;
  __syncthreads();

  for (int t = 0; t < T; ++t){
    const unsigned gen = (unsigned)(t + 1);

    // ---- A: hWh[b][sub*64..+64) (register WhT slice x LDS-broadcast h) ----
    hs[tid] = hgrp[((size_t)t*B + b)*512 + tid];      // plain (time-indexed)
    __syncthreads();
    {
      const float* hk = hs + wv*64;
      float a = 0.f;
      #pragma unroll
      for (int kk = 0; kk < 64; ++kk) a += hk[kk] * wreg[kk];
      partA[wv][l] = a;
    }
    __syncthreads();
    if (tid < 64){
      float s = ab;
      #pragma unroll
      for (int k = 0; k < 8; ++k) s += partA[k][tid];
      hwl[tid] = s;
    }
    __syncthreads();

    // ---- B: partial scores over own j-slice (feat_proj from registers) ----
    {
      const float hj = hwl[l];
      float* spw = sps + (size_t)(t*B + b)*1600 + sub;
      #pragma unroll
      for (int i = 0; i < 25; ++i){
        const int p = wv + i*8;
        if (p >= P) break;
        float e2 = vl * fast_tanh(fpreg[i] + hj);
        #pragma unroll
        for (int off = 32; off; off >>= 1) e2 += __shfl_xor(e2, off);
        if (l == 0) cohstore(spw + p*8, e2);
      }
    }
    bar_mini(fm1 + blk, fm1 + gbase, gen);

    // ---- C: reduce partials -> softmax -> ctx slice (features from regs) ----
    {
      float sc_v = -1e30f;
      if (tid < P){
        const float* sp = sps + (size_t)(t*B + b)*1600 + tid*8;
        float4 q0 = *(const float4*)sp, q1 = *(const float4*)(sp + 4);
        sc_v = (q0.x + q0.y + q0.z + q0.w) + (q1.x + q1.y + q1.z + q1.w);
      }
      if (tid < 256) aux[tid] = sc_v;
      __syncthreads();
      if (tid < 64){
        float m = -1e30f;
        #pragma unroll
        for (int i = 0; i < 4; ++i) m = fmaxf(m, aux[tid + i*64]);
        #pragma unroll
        for (int off = 32; off; off >>= 1) m = fmaxf(m, __shfl_xor(m, off));
        if (tid == 0) smx = m;
      }
      __syncthreads();
      float al = (tid < P) ? __expf(sc_v - smx) : 0.f;
      if (tid < 256) aux[tid] = al;
      __syncthreads();
      if (tid < 64){
        float s = 0.f;
        #pragma unroll
        for (int i = 0; i < 4; ++i) s += aux[tid + i*64];
        #pragma unroll
        for (int off = 32; off; off >>= 1) s += __shfl_xor(s, off);
        if (tid == 0) sinv = 1.0f/s;
      }
      __syncthreads();
      float a = 0.f;
      #pragma unroll
      for (int i = 0; i < 25; ++i){
        const int p = wv + i*8;
        if (p >= P) break;
        a += aux[p] * ftreg[i];
      }
      partA[wv][l] = a;
      __syncthreads();
      if (tid < 64){
        float s = 0.f;
        #pragma unroll
        for (int k = 0; k < 8; ++k) s += partA[k][tid];
        cohstore(ctxbuf + ((size_t)t*B + b)*512 + sub*64 + tid, s * sinv);
      }
    }
    bar_arrive(fm2 + blk, gen);

    // ---- D part 1: Whh-part dots (needs only hs; overlaps ctx publish) ----
    float acc0 = 0.f, acc1 = 0.f, acc2 = 0.f, acc3 = 0.f;
    {
      const float* hk = hs + kh*256;
      #pragma unroll 8
      for (int k = 0; k < 256; k += 4){
        acc0 += wp_h[(size_t)(k+0)*256] * hk[k+0];
        acc1 += wp_h[(size_t)(k+1)*256] * hk[k+1];
        acc2 += wp_h[(size_t)(k+2)*256] * hk[k+2];
        acc3 += wp_h[(size_t)(k+3)*256] * hk[k+3];
      }
    }
    bar_wait(fm2 + gbase, gen);

    // ---- D part 2: ctx-part dots + LSTM update ----
    ctxl[tid] = ctxbuf[((size_t)t*B + b)*512 + tid];   // plain (time-indexed)
    __syncthreads();
    {
      const float* ck = ctxl + kh*256;
      #pragma unroll 8
      for (int k = 0; k < 256; k += 4){
        acc0 += wp_c[(size_t)(k+0)*256] * ck[k+0];
        acc1 += wp_c[(size_t)(k+1)*256] * ck[k+1];
        acc2 += wp_c[(size_t)(k+2)*256] * ck[k+2];
        acc3 += wp_c[(size_t)(k+3)*256] * ck[k+3];
      }
      red[dc*2 + kh] = (acc0 + acc1) + (acc2 + acc3);
    }
    __syncthreads();
    if (tid < 64){
      const float* ge = gates_emb + ((size_t)b*T + t)*2048;
      float gv[4];
      #pragma unroll
      for (int g = 0; g < 4; ++g){
        const int c = g*64 + tid;
        gv[g] = red[c*2] + red[c*2 + 1] + biasl[c] + ge[g*512 + sub*64 + tid];
      }
      const float i_ = sigmoidf_(gv[0]);
      const float f_ = sigmoidf_(gv[1]);
      const float g_ = fast_tanh(gv[2]);
      const float o_ = sigmoidf_(gv[3]);
      const int j = sub*64 + tid;
      const float c_new = f_*c_reg + i_*g_;
      const float h_new = o_*fast_tanh(c_new);
      c_reg = c_new;
      cohstore(hgrp + ((size_t)(t+1)*B + b)*512 + j, h_new);
      const unsigned short hh = f_to_bf16(h_new);
      hall_h[((size_t)b*T + t)*512 + j] = hh;
      hall_l[((size_t)b*T + t)*512 + j] = f_to_bf16(h_new - bf16_to_f(hh));
    }
    bar_mini(fm3 + blk, fm3 + gbase, gen);
  }
}

// ---------------------------------------------------------------------------
extern "C" void kernel_launch(void* const* d_in, const int* in_sizes, int n_in,
                              void* d_out, int out_size, void* d_ws, size_t ws_size,
                              hipStream_t stream)
{
  (void)in_sizes; (void)n_in; (void)out_size;
  const float* features = (const float*)d_in[0];
  const int*   captions = (const int*)d_in[1];
  const float* embed_W  = (const float*)d_in[2];
  const float* attn_W   = (const float*)d_in[3];
  const float* attn_b   = (const float*)d_in[4];
  const float* v_w      = (const float*)d_in[5];
  const float* W_ih     = (const float*)d_in[6];
  const float* W_hh     = (const float*)d_in[7];
  const float* b_ih     = (const float*)d_in[8];
  const float* b_hh     = (const float*)d_in[9];
  const float* lin_W    = (const float*)d_in[10];
  const float* lin_b    = (const float*)d_in[11];
  const float* inith_W  = (const float*)d_in[12];
  const float* inith_b  = (const float*)d_in[13];
  const float* initc_W  = (const float*)d_in[14];
  const float* initc_b  = (const float*)d_in[15];

  // "early" scratch in d_out (131MB; all dead before final logits GEMM)
  char* o = (char*)d_out;
  unsigned short* feat_bf   = (unsigned short*)o; o += (size_t)(B*P)*E*2;   // 6.4MB
  unsigned short* Wf_bf     = (unsigned short*)o; o += (size_t)H*E*2;       // 0.5MB
  float*          feat_proj = (float*)o;          o += (size_t)(B*P)*H*4;   // 12.9MB
  unsigned short* emb_hi    = (unsigned short*)o; o += (size_t)(B*T)*E*2;   // 1.05MB
  unsigned short* emb_lo    = (unsigned short*)o; o += (size_t)(B*T)*E*2;
  unsigned short* Wihe_hi   = (unsigned short*)o; o += (size_t)2048*512*2;  // 2.1MB
  unsigned short* Wihe_lo   = (unsigned short*)o; o += (size_t)2048*512*2;
  float*          gates_emb = (float*)o;          o += (size_t)(B*T)*2048*4;// 8.4MB
  float*          Wpack     = (float*)o;          o += (size_t)8*1024*256*4;// 8.4MB

  // persistent scratch in d_ws
  const size_t SZ_LIN  = (size_t)V*H*2;               // 32.77MB
  const size_t SZ_HALL = (size_t)(B*T)*H*2;           // 1MB
  const size_t SZ_CTX  = (size_t)T*B*512*4;           // 2.1MB
  const size_t SZ_HG   = (size_t)(T+1)*B*512*4;       // 2.16MB
  const size_t SZ_SPS  = (size_t)T*B*200*8*4;         // 6.55MB
  const size_t SZ_ST   = (size_t)B*H*4;               // 64KB
  const size_t SZ_WHT  = (size_t)H*H*4;               // 1MB
  const size_t SZ_FLG  = 4096;
  const size_t need_wo = SZ_LIN + 2*SZ_HALL + SZ_CTX + SZ_HG + SZ_SPS + SZ_ST + SZ_WHT + SZ_FLG;
  const bool three = (ws_size >= need_wo + SZ_LIN);

  char* w = (char*)d_ws;
  unsigned short* lin_hi  = (unsigned short*)w; w += SZ_LIN;
  unsigned short* lin_lo  = (unsigned short*)w; if (three) w += SZ_LIN;
  unsigned short* hall_hi = (unsigned short*)w; w += SZ_HALL;
  unsigned short* hall_lo = (unsigned short*)w; w += SZ_HALL;
  float*          ctxbuf  = (float*)w;          w += SZ_CTX;
  float*          hgrp    = (float*)w;          w += SZ_HG;
  float*          sps     = (float*)w;          w += SZ_SPS;
  float*          c_state = (float*)w;          w += SZ_ST;
  float*          WhT_ws  = (float*)w;          w += SZ_WHT;
  unsigned*       flags   = (unsigned*)w;       w += SZ_FLG;
  unsigned* fm1 = flags;           // [256]
  unsigned* fm2 = flags + 256;     // [256]
  unsigned* fm3 = flags + 512;     // [256]

  // --- conversions / gathers / packs / init ---
  split_kernel<<<2048, 256, 0, stream>>>(features, E, 0, B*P, feat_bf, nullptr, E, 0);
  split_kernel<<<256, 256, 0, stream>>>(attn_W, E+H, 0, H, Wf_bf, nullptr, E, 0);
  split_kernel<<<2048, 256, 0, stream>>>(lin_W, 512, 0, V, lin_hi, three ? lin_lo : nullptr, 512, 0);
  split_kernel<<<1024, 256, 0, stream>>>(W_ih, 1024, 0, 2048, Wihe_hi, Wihe_lo, 512, 0);
  embed_kernel<<<B*T, 256, 0, stream>>>(captions, embed_W, emb_hi, emb_lo);
  prep_kernel<<<B, 512, 0, stream>>>(features, inith_W, inith_b, initc_W, initc_b,
                                     hgrp, c_state);
  transpose_wh_kernel<<<64, 256, 0, stream>>>(attn_W, WhT_ws);
  pack_wd_kernel<<<512, 256, 0, stream>>>(W_ih, W_hh, Wpack);
  hipMemsetAsync(flags, 0, SZ_FLG, stream);

  // feat_proj = features @ Wf^T (bf16 1-pass; error damped through tanh/softmax)
  gemm_bt_kernel<<<(B*P/128)*(E/128), 256, 0, stream>>>(
      feat_bf, feat_bf, feat_bf, Wf_bf, Wf_bf, Wf_bf,
      feat_proj, nullptr, E, E, 1, B*P/128, 0);
  // gates_emb = emb @ W_ih[:, :512]^T (bf16x3)
  gemm_bt_kernel<<<(B*T/128)*(2048/128), 256, 0, stream>>>(
      emb_hi, emb_lo, emb_hi, Wihe_hi, Wihe_hi, Wihe_lo,
      gates_emb, nullptr, 2048, 512, 3, B*T/128, 1);

  // --- recurrence: one persistent kernel, zero global sync ---
  loop_kernel<<<NB, NT, 0, stream>>>(
      features, feat_proj, WhT_ws, attn_b, v_w, Wpack, gates_emb, b_ih, b_hh,
      hgrp, c_state, ctxbuf, sps, hall_hi, hall_lo, fm1, fm2, fm3);

  // --- logits = h_all @ lin_W^T + lin_b (bf16x3, XCD-swizzled grid) ---
  gemm_bt_kernel<<<(V/128)*(B*T/128), 256, 0, stream>>>(
      hall_hi, hall_lo, hall_hi, lin_hi, lin_hi, three ? lin_lo : lin_hi,
      (float*)d_out, lin_b, V, H, three ? 3 : 2, B*T/128, 1);
}

// Round 18
// 1060.519 us; speedup vs baseline: 1.9950x; 1.1762x over previous
//
// CaptionDecoder on MI355X — round 18: fold ctx-gates through softmax (FW trick).
// W_ih_ctx @ ctx == sum_p alpha_p * FW[b][p][:] / S with FW = feats @ W_ih_ctx^T
// (step-invariant, precomputed bf16x3). ctx never materializes -> barrier-2
// gone (2 mini-barriers/step), D weight streaming halves (Whh only, L2-resident).
#include <hip/hip_runtime.h>

#define E 512
#define H 512
#define V 32000
#define B 32
#define P 196
#define T 32
#define NB 256
#define NT 512

typedef __attribute__((ext_vector_type(8))) short s8v;    // 8 bf16
typedef __attribute__((ext_vector_type(4))) float f4v;    // 4 f32 acc

__device__ __forceinline__ float bf16_to_f(unsigned short u){
  return __uint_as_float(((unsigned)u) << 16);
}
__device__ __forceinline__ unsigned short f_to_bf16(float f){
  unsigned u = __float_as_uint(f);
  u += 0x7FFFu + ((u >> 16) & 1u);   // RNE
  return (unsigned short)(u >> 16);
}
__device__ __forceinline__ float fast_tanh(float x){
  float e = __expf(2.0f*x);
  return 1.0f - 2.0f/(e + 1.0f);
}
__device__ __forceinline__ float sigmoidf_(float x){
  return 1.0f/(1.0f + __expf(-x));
}
__device__ __forceinline__ void load_lds16(const unsigned short* g, unsigned short* l){
  __builtin_amdgcn_global_load_lds(
      (const __attribute__((address_space(1))) void*)g,
      (__attribute__((address_space(3))) void*)l, 16, 0, 0);
}
__device__ __forceinline__ float dot4(float4 a, float4 b){
  return a.x*b.x + a.y*b.y + a.z*b.z + a.w*b.w;
}

#define AT_SCOPE __HIP_MEMORY_SCOPE_AGENT
__device__ __forceinline__ void cohstore(float* p, float v){
  __hip_atomic_store(p, v, __ATOMIC_RELAXED, AT_SCOPE);
}
__device__ __forceinline__ unsigned cohldu(const unsigned* p){
  return __hip_atomic_load(p, __ATOMIC_RELAXED, AT_SCOPE);
}
__device__ __forceinline__ void cohstu(unsigned* p, unsigned v){
  __hip_atomic_store(p, v, __ATOMIC_RELAXED, AT_SCOPE);
}

// 8-block mini-barrier, split arrive/wait (all relaxed; __syncthreads drains
// vmcnt -> block's coherent stores are LLC-visible before the flag publish).
__device__ __forceinline__ void bar_arrive(unsigned* my, unsigned gen){
  __syncthreads();
  if (threadIdx.x == 0) cohstu(my, gen);
}
__device__ __forceinline__ void bar_wait(const unsigned* base, unsigned gen){
  if (threadIdx.x < 64){
    for (;;){
      unsigned mn = 0xffffffffu;
      for (int i = (int)threadIdx.x; i < 8; i += 64){
        unsigned v = cohldu(base + i);
        mn = v < mn ? v : mn;
      }
      #pragma unroll
      for (int off = 32; off; off >>= 1){
        unsigned o2 = (unsigned)__shfl_xor((int)mn, off);
        mn = o2 < mn ? o2 : mn;
      }
      if (mn >= gen) break;
      __builtin_amdgcn_s_sleep(1);
    }
    __builtin_amdgcn_sched_barrier(0);
  }
  __syncthreads();
}

// ---------------------------------------------------------------------------
// f32 (strided) -> bf16 hi (+ optional lo residual). cols==512.
__global__ void split_kernel(const float* __restrict__ src, int src_ld, int src_coff,
                             int rows,
                             unsigned short* __restrict__ dhi, unsigned short* __restrict__ dlo,
                             int dst_ld, int dst_coff)
{
  int n = rows << 9;
  for (int i = blockIdx.x*blockDim.x + threadIdx.x; i < n; i += gridDim.x*blockDim.x){
    int r = i >> 9, c = i & 511;
    float x = src[(size_t)r*src_ld + src_coff + c];
    unsigned short h = f_to_bf16(x);
    dhi[(size_t)r*dst_ld + dst_coff + c] = h;
    if (dlo) dlo[(size_t)r*dst_ld + dst_coff + c] = f_to_bf16(x - bf16_to_f(h));
  }
}

// Embedding gather -> bf16 hi/lo rows (row = b*T + t)
__global__ void embed_kernel(const int* __restrict__ caps, const float* __restrict__ embW,
                             unsigned short* __restrict__ ehi, unsigned short* __restrict__ elo)
{
  int row = blockIdx.x;
  int cap = caps[row];
  const float* s = embW + (size_t)cap*E;
  for (int e = threadIdx.x; e < E; e += blockDim.x){
    float x = s[e];
    unsigned short h = f_to_bf16(x);
    ehi[(size_t)row*E + e] = h;
    elo[(size_t)row*E + e] = f_to_bf16(x - bf16_to_f(h));
  }
}

// mean over P, then h0 -> hgrp[0][b], c0 -> c_state
__global__ __launch_bounds__(512) void prep_kernel(
    const float* __restrict__ feats,
    const float* __restrict__ inith_W, const float* __restrict__ inith_b,
    const float* __restrict__ initc_W, const float* __restrict__ initc_b,
    float* __restrict__ hgrp, float* __restrict__ c_state)
{
  __shared__ float mf[E];
  const int b = blockIdx.x, tid = threadIdx.x;
  const float* fb = feats + (size_t)b*P*E + tid;
  float s = 0.f;
  for (int p = 0; p < P; ++p) s += fb[(size_t)p*E];
  mf[tid] = s * (1.0f/196.0f);
  __syncthreads();
  const float* wh = inith_W + (size_t)tid*E;
  const float* wc = initc_W + (size_t)tid*E;
  float h0 = inith_b[tid], c0 = initc_b[tid];
  #pragma unroll 4
  for (int e = 0; e < E; e += 4){
    float4 a4 = *(const float4*)(wh + e);
    float4 b4 = *(const float4*)(wc + e);
    float4 m4 = *(const float4*)(mf + e);
    h0 += dot4(a4, m4);
    c0 += dot4(b4, m4);
  }
  hgrp[(size_t)b*512 + tid] = h0;
  c_state[b*512 + tid] = c0;
}

// WhT[k][j] = attn_W[j][E + k]
__global__ __launch_bounds__(256) void transpose_wh_kernel(
    const float* __restrict__ attn_W, float* __restrict__ WhT)
{
  __shared__ float tile[64][65];
  const int jt = blockIdx.x & 7, kt = blockIdx.x >> 3;
  const int tx = threadIdx.x & 63, ty = threadIdx.x >> 6;
  for (int r = ty; r < 64; r += 4)
    tile[r][tx] = attn_W[(size_t)(jt*64 + r)*(E+H) + E + kt*64 + tx];
  __syncthreads();
  for (int r = ty; r < 64; r += 4)
    WhT[(size_t)(kt*64 + r)*512 + jt*64 + tx] = tile[tx][r];
}

// Wpackh[sub][k][c]: k in [0,512) = Whh row of gate col; c in [0,256):
// gcol = (c>>6)*512 + sub*64 + (c&63). Coalesced repack.
__global__ __launch_bounds__(256) void pack_whh_kernel(
    const float* __restrict__ Whh, float* __restrict__ Wpackh)
{
  __shared__ float tile[64][65];
  const int sub = blockIdx.x & 7, cg = (blockIdx.x >> 3) & 3, kg = blockIdx.x >> 5;
  const int tx = threadIdx.x & 63, ty = threadIdx.x >> 6;
  const int kbase = kg*64;
  for (int cl = ty; cl < 64; cl += 4){
    const int c = cg*64 + cl;
    const int gcol = (c >> 6)*512 + sub*64 + (c & 63);
    tile[cl][tx] = Whh[(size_t)gcol*512 + kbase + tx];
  }
  __syncthreads();
  for (int kk = ty; kk < 64; kk += 4)
    Wpackh[((size_t)sub*512 + kbase + kk)*256 + cg*64 + tx] = tile[tx][kk];
}

// ---------------------------------------------------------------------------
// m97-style bf16 GEMM: C = sum_passes A_p (MxK) * B_p(NxK)^T [+bias]
__global__ __launch_bounds__(256) void gemm_bt_kernel(
    const unsigned short* __restrict__ A0, const unsigned short* __restrict__ A1,
    const unsigned short* __restrict__ A2,
    const unsigned short* __restrict__ B0, const unsigned short* __restrict__ B1,
    const unsigned short* __restrict__ B2,
    float* __restrict__ Cc, const float* __restrict__ bias,
    int N, int K, int npasses, int mt, int swz)
{
  __shared__ __align__(16) unsigned short Al[128*32];
  __shared__ __align__(16) unsigned short Bl[128*32];
  const int tid = threadIdx.x;
  const int wid = tid >> 6, l = tid & 63;
  int f = blockIdx.x;
  if (swz) f = (f & 7)*((int)gridDim.x >> 3) + (f >> 3);
  const int m0 = (f % mt)*128, n0 = (f / mt)*128;
  const int wr = wid >> 1, wc = wid & 1;

  f4v acc[4][4];
  #pragma unroll
  for (int i = 0; i < 4; ++i)
    #pragma unroll
    for (int j = 0; j < 4; ++j) acc[i][j] = (f4v){0.f,0.f,0.f,0.f};

  const int s0 = tid, s1 = tid + 256;
  const int r0 = s0 >> 2, g0 = (s0 & 3) ^ ((r0 >> 1) & 3);
  const int r1 = s1 >> 2, g1 = (s1 & 3) ^ ((r1 >> 1) & 3);
  const int la = l & 15, ch = l >> 4;

  for (int pass = 0; pass < npasses; ++pass){
    const unsigned short* Ap = pass == 0 ? A0 : (pass == 1 ? A1 : A2);
    const unsigned short* Bp = pass == 0 ? B0 : (pass == 1 ? B1 : B2);
    for (int k0 = 0; k0 < K; k0 += 32){
      __syncthreads();
      load_lds16(Ap + (size_t)(m0 + r0)*K + k0 + g0*8, Al + s0*8);
      load_lds16(Ap + (size_t)(m0 + r1)*K + k0 + g1*8, Al + s1*8);
      load_lds16(Bp + (size_t)(n0 + r0)*K + k0 + g0*8, Bl + s0*8);
      load_lds16(Bp + (size_t)(n0 + r1)*K + k0 + g1*8, Bl + s1*8);
      __syncthreads();
      s8v av[4], bv[4];
      #pragma unroll
      for (int mi = 0; mi < 4; ++mi){
        int row = wr*64 + mi*16 + la;
        int cs = ch ^ ((row >> 1) & 3);
        av[mi] = *(const s8v*)(Al + (row*4 + cs)*8);
      }
      #pragma unroll
      for (int ni = 0; ni < 4; ++ni){
        int row = wc*64 + ni*16 + la;
        int cs = ch ^ ((row >> 1) & 3);
        bv[ni] = *(const s8v*)(Bl + (row*4 + cs)*8);
      }
      #pragma unroll
      for (int mi = 0; mi < 4; ++mi)
        #pragma unroll
        for (int ni = 0; ni < 4; ++ni)
          acc[mi][ni] = __builtin_amdgcn_mfma_f32_16x16x32_bf16(av[mi], bv[ni], acc[mi][ni], 0, 0, 0);
    }
  }
  #pragma unroll
  for (int mi = 0; mi < 4; ++mi){
    int row = m0 + wr*64 + mi*16 + (l >> 4)*4;
    #pragma unroll
    for (int ni = 0; ni < 4; ++ni){
      int col = n0 + wc*64 + ni*16 + (l & 15);
      float bb = bias ? bias[col] : 0.0f;
      #pragma unroll
      for (int r = 0; r < 4; ++r)
        Cc[(size_t)(row + r)*N + col] = acc[mi][ni][r] + bb;
    }
  }
}

// ---------------------------------------------------------------------------
// Persistent loop kernel, batch-local groups, zero global sync, 2 minis/step.
// blk = b*8 + sub (same-sub blocks share an XCD -> Wpackh[sub] 0.5MB L2-res).
// Block owns j-slice sub*64..+64 x 4 gates of ITS batch.
// ctx-gate term via FW: acc_ctx = sum_p aux[p]*FW[b][p][gcol], scaled by sinv.
// Per step: [ge pf] A,B | arrive1 | D-h | wait1 | softmax | D-ctx | update |
//           arrive3 | hall stores | wait3.
__global__ __launch_bounds__(512, 1) void loop_kernel(
    const float* __restrict__ feat_proj,
    const float* __restrict__ WhT, const float* __restrict__ attn_b,
    const float* __restrict__ v_w, const float* __restrict__ Wpackh,
    const float* __restrict__ FW, const float* __restrict__ gates_emb,
    const float* __restrict__ b_ih, const float* __restrict__ b_hh,
    float* __restrict__ hgrp,          // [T+1][B][512]
    const float* __restrict__ c_init,
    float* __restrict__ sps,           // [T][B][200][8]
    unsigned short* __restrict__ hall_h, unsigned short* __restrict__ hall_l,
    unsigned* __restrict__ fm1, unsigned* __restrict__ fm3)
{
  __shared__ float hs[512];
  __shared__ float hwl[64];
  __shared__ float partA[8][72];
  __shared__ float aux[256];
  __shared__ float biasl[256];
  __shared__ float red[512];
  __shared__ float smx, sinv;

  const int blk = blockIdx.x, tid = threadIdx.x;
  const int b = blk >> 3, sub = blk & 7;
  const int gbase = blk & ~7;
  const int l = tid & 63, wv = tid >> 6;

  // ---- prologue ----
  float wreg[64];
  #pragma unroll
  for (int kk = 0; kk < 64; ++kk)
    wreg[kk] = WhT[(size_t)(wv*64 + kk)*512 + sub*64 + l];
  float fpreg[25];
  #pragma unroll
  for (int i = 0; i < 25; ++i){
    const int p = wv + i*8;
    fpreg[i] = (p < P) ? feat_proj[((size_t)b*P + p)*512 + sub*64 + l] : 0.f;
  }
  for (int c = tid; c < 256; c += NT){
    const int gcol = (c >> 6)*512 + sub*64 + (c & 63);
    biasl[c] = b_ih[gcol] + b_hh[gcol];
  }
  const float vl = v_w[sub*64 + l];
  const float ab = (tid < 64) ? attn_b[sub*64 + tid] : 0.f;
  float c_reg = 0.f;
  if (tid < 64) c_reg = c_init[b*512 + sub*64 + tid];

  // phase-D decomposition: thread = (dc: block-local col, kh: half)
  const int dc = tid & 255;
  const int kh = tid >> 8;
  const int gcol_d = (dc >> 6)*512 + sub*64 + (dc & 63);
  const float* wp_h = Wpackh + ((size_t)sub*512 + kh*256)*256 + dc;
  __syncthreads();

  for (int t = 0; t < T; ++t){
    const unsigned gen = (unsigned)(t + 1);

    // ---- gates_emb prefetch (hidden under A/B/D-h) ----
    float gepre[4];
    if (tid < 64){
      const float* ge = gates_emb + ((size_t)b*T + t)*2048;
      #pragma unroll
      for (int g = 0; g < 4; ++g) gepre[g] = ge[g*512 + sub*64 + tid];
    }

    // ---- A: hWh[b][sub*64..+64) (register WhT slice x LDS-broadcast h) ----
    hs[tid] = hgrp[((size_t)t*B + b)*512 + tid];      // plain (time-indexed)
    __syncthreads();
    {
      const float* hk = hs + wv*64;
      float a = 0.f;
      #pragma unroll
      for (int kk = 0; kk < 64; ++kk) a += hk[kk] * wreg[kk];
      partA[wv][l] = a;
    }
    __syncthreads();
    if (tid < 64){
      float s = ab;
      #pragma unroll
      for (int k = 0; k < 8; ++k) s += partA[k][tid];
      hwl[tid] = s;
    }
    __syncthreads();

    // ---- B: partial scores over own j-slice (feat_proj from registers) ----
    {
      const float hj = hwl[l];
      float* spw = sps + (size_t)(t*B + b)*1600 + sub;
      #pragma unroll
      for (int i = 0; i < 25; ++i){
        const int p = wv + i*8;
        if (p >= P) break;
        float e2 = vl * fast_tanh(fpreg[i] + hj);
        #pragma unroll
        for (int off = 32; off; off >>= 1) e2 += __shfl_xor(e2, off);
        if (l == 0) cohstore(spw + p*8, e2);
      }
    }
    bar_arrive(fm1 + blk, gen);

    // ---- D-h: Whh-part dots (needs only hs; hides mini1 window) ----
    float acch0 = 0.f, acch1 = 0.f, acch2 = 0.f, acch3 = 0.f;
    {
      const float* hk = hs + kh*256;
      #pragma unroll 8
      for (int k = 0; k < 256; k += 4){
        acch0 += wp_h[(size_t)(k+0)*256] * hk[k+0];
        acch1 += wp_h[(size_t)(k+1)*256] * hk[k+1];
        acch2 += wp_h[(size_t)(k+2)*256] * hk[k+2];
        acch3 += wp_h[(size_t)(k+3)*256] * hk[k+3];
      }
    }
    bar_wait(fm1 + gbase, gen);

    // ---- softmax (redundant x8, all operands local/plain) ----
    {
      float sc_v = -1e30f;
      if (tid < P){
        const float* sp = sps + (size_t)(t*B + b)*1600 + tid*8;
        float4 q0 = *(const float4*)sp, q1 = *(const float4*)(sp + 4);
        sc_v = (q0.x + q0.y + q0.z + q0.w) + (q1.x + q1.y + q1.z + q1.w);
      }
      if (tid < 256) aux[tid] = sc_v;
      __syncthreads();
      if (tid < 64){
        float m = -1e30f;
        #pragma unroll
        for (int i = 0; i < 4; ++i) m = fmaxf(m, aux[tid + i*64]);
        #pragma unroll
        for (int off = 32; off; off >>= 1) m = fmaxf(m, __shfl_xor(m, off));
        if (tid == 0) smx = m;
      }
      __syncthreads();
      float al = (tid < P) ? __expf(sc_v - smx) : 0.f;
      if (tid < 256) aux[tid] = al;
      __syncthreads();
      if (tid < 64){
        float s = 0.f;
        #pragma unroll
        for (int i = 0; i < 4; ++i) s += aux[tid + i*64];
        #pragma unroll
        for (int off = 32; off; off >>= 1) s += __shfl_xor(s, off);
        if (tid == 0) sinv = 1.0f/s;
      }
      __syncthreads();
    }

    // ---- D-ctx: rank-P contraction against precomputed FW ----
    float accc = 0.f;
    {
      const float* fwb = FW + ((size_t)b*P + kh*98)*2048 + gcol_d;
      const float* ax = aux + kh*98;
      #pragma unroll 7
      for (int i = 0; i < 98; ++i)
        accc += ax[i] * fwb[(size_t)i*2048];
    }
    red[dc*2 + kh] = ((acch0 + acch1) + (acch2 + acch3)) + accc*sinv;
    __syncthreads();

    // ---- LSTM update ----
    if (tid < 64){
      float gv[4];
      #pragma unroll
      for (int g = 0; g < 4; ++g){
        const int c = g*64 + tid;
        gv[g] = red[c*2] + red[c*2 + 1] + biasl[c] + gepre[g];
      }
      const float i_ = sigmoidf_(gv[0]);
      const float f_ = sigmoidf_(gv[1]);
      const float g_ = fast_tanh(gv[2]);
      const float o_ = sigmoidf_(gv[3]);
      const int j = sub*64 + tid;
      const float c_new = f_*c_reg + i_*g_;
      const float h_new = o_*fast_tanh(c_new);
      c_reg = c_new;
      cohstore(hgrp + ((size_t)(t+1)*B + b)*512 + j, h_new);
      const unsigned short hh = f_to_bf16(h_new);
      aux[tid] = __uint_as_float(((unsigned)hh << 16) |
                 (unsigned)f_to_bf16(h_new - bf16_to_f(hh)));
    }
    bar_arrive(fm3 + blk, gen);
    if (tid < 64){
      const unsigned pk = __float_as_uint(aux[tid]);
      const int j = sub*64 + tid;
      hall_h[((size_t)b*T + t)*512 + j] = (unsigned short)(pk >> 16);
      hall_l[((size_t)b*T + t)*512 + j] = (unsigned short)(pk & 0xffffu);
    }
    bar_wait(fm3 + gbase, gen);
  }
}

// ---------------------------------------------------------------------------
extern "C" void kernel_launch(void* const* d_in, const int* in_sizes, int n_in,
                              void* d_out, int out_size, void* d_ws, size_t ws_size,
                              hipStream_t stream)
{
  (void)in_sizes; (void)n_in; (void)out_size;
  const float* features = (const float*)d_in[0];
  const int*   captions = (const int*)d_in[1];
  const float* embed_W  = (const float*)d_in[2];
  const float* attn_W   = (const float*)d_in[3];
  const float* attn_b   = (const float*)d_in[4];
  const float* v_w      = (const float*)d_in[5];
  const float* W_ih     = (const float*)d_in[6];
  const float* W_hh     = (const float*)d_in[7];
  const float* b_ih     = (const float*)d_in[8];
  const float* b_hh     = (const float*)d_in[9];
  const float* lin_W    = (const float*)d_in[10];
  const float* lin_b    = (const float*)d_in[11];
  const float* inith_W  = (const float*)d_in[12];
  const float* inith_b  = (const float*)d_in[13];
  const float* initc_W  = (const float*)d_in[14];
  const float* initc_b  = (const float*)d_in[15];

  // "early" scratch in d_out (~101MB; all dead before final logits GEMM)
  char* o = (char*)d_out;
  unsigned short* feat_hi   = (unsigned short*)o; o += (size_t)(B*P)*E*2;   // 6.4MB
  unsigned short* feat_lo   = (unsigned short*)o; o += (size_t)(B*P)*E*2;   // 6.4MB
  unsigned short* Wf_bf     = (unsigned short*)o; o += (size_t)H*E*2;       // 0.5MB
  float*          feat_proj = (float*)o;          o += (size_t)(B*P)*H*4;   // 12.9MB
  unsigned short* emb_hi    = (unsigned short*)o; o += (size_t)(B*T)*E*2;   // 1.05MB
  unsigned short* emb_lo    = (unsigned short*)o; o += (size_t)(B*T)*E*2;
  unsigned short* Wihe_hi   = (unsigned short*)o; o += (size_t)2048*512*2;  // 2.1MB
  unsigned short* Wihe_lo   = (unsigned short*)o; o += (size_t)2048*512*2;
  unsigned short* Wihc_hi   = (unsigned short*)o; o += (size_t)2048*512*2;  // 2.1MB
  unsigned short* Wihc_lo   = (unsigned short*)o; o += (size_t)2048*512*2;
  float*          gates_emb = (float*)o;          o += (size_t)(B*T)*2048*4;// 8.4MB
  float*          Wpackh    = (float*)o;          o += (size_t)8*512*256*4; // 4.2MB
  float*          FW        = (float*)o;          o += (size_t)(B*P)*2048*4;// 51.4MB

  // persistent scratch in d_ws
  const size_t SZ_LIN  = (size_t)V*H*2;               // 32.77MB
  const size_t SZ_HALL = (size_t)(B*T)*H*2;           // 1MB
  const size_t SZ_HG   = (size_t)(T+1)*B*512*4;       // 2.16MB
  const size_t SZ_SPS  = (size_t)T*B*200*8*4;         // 6.55MB
  const size_t SZ_ST   = (size_t)B*H*4;               // 64KB
  const size_t SZ_WHT  = (size_t)H*H*4;               // 1MB
  const size_t SZ_FLG  = 4096;
  const size_t need_wo = SZ_LIN + 2*SZ_HALL + SZ_HG + SZ_SPS + SZ_ST + SZ_WHT + SZ_FLG;
  const bool three = (ws_size >= need_wo + SZ_LIN);

  char* w = (char*)d_ws;
  unsigned short* lin_hi  = (unsigned short*)w; w += SZ_LIN;
  unsigned short* lin_lo  = (unsigned short*)w; if (three) w += SZ_LIN;
  unsigned short* hall_hi = (unsigned short*)w; w += SZ_HALL;
  unsigned short* hall_lo = (unsigned short*)w; w += SZ_HALL;
  float*          hgrp    = (float*)w;          w += SZ_HG;
  float*          sps     = (float*)w;          w += SZ_SPS;
  float*          c_state = (float*)w;          w += SZ_ST;
  float*          WhT_ws  = (float*)w;          w += SZ_WHT;
  unsigned*       flags   = (unsigned*)w;       w += SZ_FLG;
  unsigned* fm1 = flags;           // [256]
  unsigned* fm3 = flags + 256;     // [256]

  // --- conversions / gathers / packs / init ---
  split_kernel<<<2048, 256, 0, stream>>>(features, E, 0, B*P, feat_hi, feat_lo, E, 0);
  split_kernel<<<256, 256, 0, stream>>>(attn_W, E+H, 0, H, Wf_bf, nullptr, E, 0);
  split_kernel<<<2048, 256, 0, stream>>>(lin_W, 512, 0, V, lin_hi, three ? lin_lo : nullptr, 512, 0);
  split_kernel<<<1024, 256, 0, stream>>>(W_ih, 1024, 0, 2048, Wihe_hi, Wihe_lo, 512, 0);
  split_kernel<<<1024, 256, 0, stream>>>(W_ih, 1024, 512, 2048, Wihc_hi, Wihc_lo, 512, 0);
  embed_kernel<<<B*T, 256, 0, stream>>>(captions, embed_W, emb_hi, emb_lo);
  prep_kernel<<<B, 512, 0, stream>>>(features, inith_W, inith_b, initc_W, initc_b,
                                     hgrp, c_state);
  transpose_wh_kernel<<<64, 256, 0, stream>>>(attn_W, WhT_ws);
  pack_whh_kernel<<<256, 256, 0, stream>>>(W_hh, Wpackh);
  hipMemsetAsync(flags, 0, SZ_FLG, stream);

  // feat_proj = features @ Wf^T (bf16 1-pass; error damped through tanh/softmax)
  gemm_bt_kernel<<<(B*P/128)*(E/128), 256, 0, stream>>>(
      feat_hi, feat_hi, feat_hi, Wf_bf, Wf_bf, Wf_bf,
      feat_proj, nullptr, E, E, 1, B*P/128, 0);
  // gates_emb = emb @ W_ih[:, :512]^T (bf16x3)
  gemm_bt_kernel<<<(B*T/128)*(2048/128), 256, 0, stream>>>(
      emb_hi, emb_lo, emb_hi, Wihe_hi, Wihe_hi, Wihe_lo,
      gates_emb, nullptr, 2048, 512, 3, B*T/128, 1);
  // FW = features @ W_ih[:, 512:]^T (bf16x3) — the ctx-gate precompute
  gemm_bt_kernel<<<(B*P/128)*(2048/128), 256, 0, stream>>>(
      feat_hi, feat_lo, feat_hi, Wihc_hi, Wihc_hi, Wihc_lo,
      FW, nullptr, 2048, 512, 3, B*P/128, 1);

  // --- recurrence: one persistent kernel, zero global sync, 2 minis/step ---
  loop_kernel<<<NB, NT, 0, stream>>>(
      feat_proj, WhT_ws, attn_b, v_w, Wpackh, FW, gates_emb, b_ih, b_hh,
      hgrp, c_state, sps, hall_hi, hall_lo, fm1, fm3);

  // --- logits = h_all @ lin_W^T + lin_b (bf16x3, XCD-swizzled grid) ---
  gemm_bt_kernel<<<(V/128)*(B*T/128), 256, 0, stream>>>(
      hall_hi, hall_lo, hall_hi, lin_hi, lin_hi, three ? lin_lo : lin_hi,
      (float*)d_out, lin_b, V, H, three ? 3 : 2, B*T/128, 1);
}